// Round 4
// baseline (756.494 us; speedup 1.0000x reference)
//
#include <hip/hip_runtime.h>
#include <hip/hip_bf16.h>

#define N_NODES 50000
#define N_EDGES 800000
#define ET (N_EDGES + N_NODES)   // edges + self loops
#define IN_DIM 128
#define H1DIM 64                 // HEADS*HID
#define HEADS 8
#define HID 8
#define OUT_DIM 64
#define NEG_SLOPE 0.2f

// monotone float<->uint encoding for atomicMax on floats
__device__ __forceinline__ unsigned enc_f(float f) {
    unsigned b = __float_as_uint(f);
    return (b & 0x80000000u) ? ~b : (b | 0x80000000u);
}
__device__ __forceinline__ float dec_f(unsigned e) {
    unsigned b = (e & 0x80000000u) ? (e & 0x7fffffffu) : ~e;
    return __uint_as_float(b);
}

// edge_index arrives as int32 (harness converts integer inputs to int)
__device__ __forceinline__ void edge_nodes(const int* __restrict__ ei, int e, int& s, int& d) {
    if (e < N_EDGES) { s = ei[e]; d = ei[N_EDGES + e]; }
    else             { s = e - N_EDGES; d = s; }
}

__device__ __forceinline__ float lrelu(float v) { return v >= 0.f ? v : NEG_SLOPE * v; }

__global__ void zero_kernel(float* __restrict__ p, int n) {
    int i = blockIdx.x * blockDim.x + threadIdx.x;
    if (i < n) p[i] = 0.f;
}

// h1 = x @ W1 ; per-head scores
__global__ __launch_bounds__(64) void lin1_kernel(
    const float* __restrict__ x, const float* __restrict__ W1,
    const float* __restrict__ a_src, const float* __restrict__ a_dst,
    float* __restrict__ h1, float* __restrict__ ssrc, float* __restrict__ sdst)
{
    int n = blockIdx.x, t = threadIdx.x;
    __shared__ float xr[IN_DIM];
    __shared__ float rs[H1DIM], rd[H1DIM];
    for (int k = t; k < IN_DIM; k += 64) xr[k] = x[n * IN_DIM + k];
    __syncthreads();
    float acc = 0.f;
    #pragma unroll 4
    for (int k = 0; k < IN_DIM; ++k) acc += xr[k] * W1[k * H1DIM + t];
    h1[n * H1DIM + t] = acc;
    rs[t] = acc * a_src[t];
    rd[t] = acc * a_dst[t];
    __syncthreads();
    if (t < HEADS) {
        float s = 0.f, d = 0.f;
        #pragma unroll
        for (int c = 0; c < HID; ++c) { s += rs[t * HID + c]; d += rd[t * HID + c]; }
        ssrc[n * HEADS + t] = s;
        sdst[n * HEADS + t] = d;
    }
}

__global__ void emax1_kernel(const int* __restrict__ ei,
                             const float* __restrict__ ssrc, const float* __restrict__ sdst,
                             unsigned* __restrict__ menc)
{
    int i = blockIdx.x * blockDim.x + threadIdx.x;
    if (i >= ET * HEADS) return;
    int e = i >> 3, h = i & 7;
    int s, d; edge_nodes(ei, e, s, d);
    float v = lrelu(ssrc[s * HEADS + h] + sdst[d * HEADS + h]);
    atomicMax(&menc[d * HEADS + h], enc_f(v));
}

__global__ void esum1_kernel(const int* __restrict__ ei,
                             const float* __restrict__ ssrc, const float* __restrict__ sdst,
                             const unsigned* __restrict__ menc, float* __restrict__ den)
{
    int i = blockIdx.x * blockDim.x + threadIdx.x;
    if (i >= ET * HEADS) return;
    int e = i >> 3, h = i & 7;
    int s, d; edge_nodes(ei, e, s, d);
    float v = lrelu(ssrc[s * HEADS + h] + sdst[d * HEADS + h]);
    float m = dec_f(menc[d * HEADS + h]);
    atomicAdd(&den[d * HEADS + h], expf(v - m));
}

__global__ void eaggr1_kernel(const int* __restrict__ ei,
                              const float* __restrict__ ssrc, const float* __restrict__ sdst,
                              const unsigned* __restrict__ menc, const float* __restrict__ den,
                              const float* __restrict__ h1, float* __restrict__ o1)
{
    long long i = (long long)blockIdx.x * blockDim.x + threadIdx.x;
    if (i >= (long long)ET * 64) return;
    int e = (int)(i >> 6), t = (int)(i & 63);
    int h = t >> 3;
    int s, d; edge_nodes(ei, e, s, d);
    float v = lrelu(ssrc[s * HEADS + h] + sdst[d * HEADS + h]);
    float m = dec_f(menc[d * HEADS + h]);
    float alpha = expf(v - m) / (den[d * HEADS + h] + 1e-16f);
    atomicAdd(&o1[d * 64 + t], h1[s * 64 + t] * alpha);
}

__global__ void elu_kernel(float* __restrict__ o1, const float* __restrict__ b1) {
    int i = blockIdx.x * blockDim.x + threadIdx.x;
    if (i >= N_NODES * 64) return;
    float v = o1[i] + b1[i & 63];
    o1[i] = v > 0.f ? v : expm1f(v);
}

// h2 = hact @ W2 ; single-head scores (dot over 64 channels)
__global__ __launch_bounds__(64) void lin2_kernel(
    const float* __restrict__ hact, const float* __restrict__ W2,
    const float* __restrict__ a_src, const float* __restrict__ a_dst,
    float* __restrict__ h2, float* __restrict__ ssrc, float* __restrict__ sdst)
{
    int n = blockIdx.x, t = threadIdx.x;
    __shared__ float xr[64];
    __shared__ float rs[64], rd[64];
    xr[t] = hact[n * 64 + t];
    __syncthreads();
    float acc = 0.f;
    #pragma unroll 4
    for (int k = 0; k < 64; ++k) acc += xr[k] * W2[k * 64 + t];
    h2[n * 64 + t] = acc;
    rs[t] = acc * a_src[t];
    rd[t] = acc * a_dst[t];
    __syncthreads();
    for (int off = 32; off > 0; off >>= 1) {
        if (t < off) { rs[t] += rs[t + off]; rd[t] += rd[t + off]; }
        __syncthreads();
    }
    if (t == 0) { ssrc[n] = rs[0]; sdst[n] = rd[0]; }
}

__global__ void emax2_kernel(const int* __restrict__ ei,
                             const float* __restrict__ ssrc, const float* __restrict__ sdst,
                             unsigned* __restrict__ menc)
{
    int e = blockIdx.x * blockDim.x + threadIdx.x;
    if (e >= ET) return;
    int s, d; edge_nodes(ei, e, s, d);
    float v = lrelu(ssrc[s] + sdst[d]);
    atomicMax(&menc[d], enc_f(v));
}

__global__ void esum2_kernel(const int* __restrict__ ei,
                             const float* __restrict__ ssrc, const float* __restrict__ sdst,
                             const unsigned* __restrict__ menc, float* __restrict__ den)
{
    int e = blockIdx.x * blockDim.x + threadIdx.x;
    if (e >= ET) return;
    int s, d; edge_nodes(ei, e, s, d);
    float v = lrelu(ssrc[s] + sdst[d]);
    float m = dec_f(menc[d]);
    atomicAdd(&den[d], expf(v - m));
}

__global__ void eaggr2_kernel(const int* __restrict__ ei,
                              const float* __restrict__ ssrc, const float* __restrict__ sdst,
                              const unsigned* __restrict__ menc, const float* __restrict__ den,
                              const float* __restrict__ h2, float* __restrict__ o2)
{
    long long i = (long long)blockIdx.x * blockDim.x + threadIdx.x;
    if (i >= (long long)ET * 64) return;
    int e = (int)(i >> 6), t = (int)(i & 63);
    int s, d; edge_nodes(ei, e, s, d);
    float v = lrelu(ssrc[s] + sdst[d]);
    float m = dec_f(menc[d]);
    float alpha = expf(v - m) / (den[d] + 1e-16f);
    atomicAdd(&o2[d * 64 + t], h2[s * 64 + t] * alpha);
}

__global__ void finalize_kernel(const float* __restrict__ o2, const float* __restrict__ b2,
                                float* __restrict__ out)
{
    int i = blockIdx.x * blockDim.x + threadIdx.x;
    if (i >= N_NODES * 64) return;
    out[i] = o2[i] + b2[i & 63];
}

extern "C" void kernel_launch(void* const* d_in, const int* in_sizes, int n_in,
                              void* d_out, int out_size, void* d_ws, size_t ws_size,
                              hipStream_t stream)
{
    const float* x   = (const float*)d_in[0];
    const int* ei    = (const int*)d_in[1];
    const float* W1  = (const float*)d_in[2];
    const float* as1 = (const float*)d_in[3];
    const float* ad1 = (const float*)d_in[4];
    const float* b1  = (const float*)d_in[5];
    const float* W2  = (const float*)d_in[6];
    const float* as2 = (const float*)d_in[7];
    const float* ad2 = (const float*)d_in[8];
    const float* b2  = (const float*)d_in[9];
    float* out = (float*)d_out;

    float* ws = (float*)d_ws;
    float*    h1 = ws;                              // N*64 (also h2 later)
    float*    o1 = h1 + N_NODES * 64;               // N*64 acc1 -> hact -> acc2
    unsigned* m1 = (unsigned*)(o1 + N_NODES * 64);  // N*8
    float*    d1 = (float*)(m1 + N_NODES * 8);      // N*8
    unsigned* m2 = (unsigned*)(d1 + N_NODES * 8);   // N
    float*    d2 = (float*)(m2 + N_NODES);          // N
    float*    s1 = d2 + N_NODES;                    // N*8  ssrc1
    float*    t1 = s1 + N_NODES * 8;                // N*8  sdst1
    float*    s2 = t1 + N_NODES * 8;                // N    ssrc2
    float*    t2 = s2 + N_NODES;                    // N    sdst2

    const int B = 256;
    // zero o1,m1,d1,m2,d2 (contiguous): N*(64+8+8+1+1) floats
    int zn = N_NODES * 82;
    zero_kernel<<<(zn + B - 1) / B, B, 0, stream>>>(o1, zn);

    lin1_kernel<<<N_NODES, 64, 0, stream>>>(x, W1, as1, ad1, h1, s1, t1);

    int eh = ET * HEADS;
    emax1_kernel<<<(eh + B - 1) / B, B, 0, stream>>>(ei, s1, t1, m1);
    esum1_kernel<<<(eh + B - 1) / B, B, 0, stream>>>(ei, s1, t1, m1, d1);
    long long ec = (long long)ET * 64;
    eaggr1_kernel<<<(unsigned)((ec + B - 1) / B), B, 0, stream>>>(ei, s1, t1, m1, d1, h1, o1);

    int nn = N_NODES * 64;
    elu_kernel<<<(nn + B - 1) / B, B, 0, stream>>>(o1, b1);

    lin2_kernel<<<N_NODES, 64, 0, stream>>>(o1, W2, as2, ad2, h1, s2, t2);

    // re-zero o1 for layer-2 accumulation
    zero_kernel<<<(nn + B - 1) / B, B, 0, stream>>>(o1, nn);

    emax2_kernel<<<(ET + B - 1) / B, B, 0, stream>>>(ei, s2, t2, m2);
    esum2_kernel<<<(ET + B - 1) / B, B, 0, stream>>>(ei, s2, t2, m2, d2);
    eaggr2_kernel<<<(unsigned)((ec + B - 1) / B), B, 0, stream>>>(ei, s2, t2, m2, d2, h1, o1);

    finalize_kernel<<<(nn + B - 1) / B, B, 0, stream>>>(o1, b2, out);
}

// Round 5
// 569.524 us; speedup vs baseline: 1.3283x; 1.3283x over previous
//
#include <hip/hip_runtime.h>
#include <hip/hip_bf16.h>
#include <math.h>

#define N_NODES 50000
#define N_EDGES 800000
#define ET (N_EDGES + N_NODES)   // edges + self loops
#define IN_DIM 128
#define H1DIM 64                 // HEADS*HID
#define HEADS 8
#define HID 8
#define OUT_DIM 64
#define NEG_SLOPE 0.2f

__device__ __forceinline__ float lrelu(float v) { return v >= 0.f ? v : NEG_SLOPE * v; }

// edge_index is int32 on device (validated round 4)
__device__ __forceinline__ void edge_nodes(const int* __restrict__ ei, int e, int& s, int& d) {
    if (e < N_EDGES) { s = ei[e]; d = ei[N_EDGES + e]; }
    else             { s = e - N_EDGES; d = s; }
}

// ---------------- CSR build (by dst) ----------------

__global__ void count_kernel(const int* __restrict__ ei, int* __restrict__ cnt) {
    int i = blockIdx.x * blockDim.x + threadIdx.x;
    if (i >= ET) return;
    int s, d; edge_nodes(ei, i, s, d);
    atomicAdd(&cnt[d], 1);
}

// single-block exclusive scan; writes row[] and turns cnt[] into cursor[] in place
__global__ __launch_bounds__(1024) void scan_kernel(int* __restrict__ cnt, int* __restrict__ row) {
    __shared__ int part[1024];
    int tid = threadIdx.x;
    const int per = (N_NODES + 1023) / 1024;   // 49
    int lo = tid * per, hi = lo + per; if (hi > N_NODES) hi = N_NODES; if (lo > N_NODES) lo = N_NODES;
    int s = 0;
    for (int i = lo; i < hi; ++i) s += cnt[i];
    part[tid] = s;
    __syncthreads();
    // Hillis-Steele inclusive scan
    for (int off = 1; off < 1024; off <<= 1) {
        int v = part[tid];
        int add = (tid >= off) ? part[tid - off] : 0;
        __syncthreads();
        part[tid] = v + add;
        __syncthreads();
    }
    int off = (tid == 0) ? 0 : part[tid - 1];
    for (int i = lo; i < hi; ++i) {
        int c = cnt[i];
        row[i] = off;
        cnt[i] = off;   // becomes cursor
        off += c;
    }
    if (tid == 1023) row[N_NODES] = part[1023];
}

__global__ void fill_kernel(const int* __restrict__ ei, int* __restrict__ cursor, int* __restrict__ adj) {
    int i = blockIdx.x * blockDim.x + threadIdx.x;
    if (i >= ET) return;
    int s, d; edge_nodes(ei, i, s, d);
    int pos = atomicAdd(&cursor[d], 1);
    adj[pos] = s;
}

// ---------------- layer-1 linear: h1 = x @ W1, per-head scores ----------------

__global__ __launch_bounds__(64) void lin1_kernel(
    const float* __restrict__ x, const float* __restrict__ W1,
    const float* __restrict__ a_src, const float* __restrict__ a_dst,
    float* __restrict__ h1, float* __restrict__ ssrc, float* __restrict__ sdst)
{
    int n = blockIdx.x, t = threadIdx.x;
    __shared__ float xr[IN_DIM];
    __shared__ float rs[H1DIM], rd[H1DIM];
    for (int k = t; k < IN_DIM; k += 64) xr[k] = x[n * IN_DIM + k];
    __syncthreads();
    float acc = 0.f;
    #pragma unroll 4
    for (int k = 0; k < IN_DIM; ++k) acc += xr[k] * W1[k * H1DIM + t];
    h1[n * H1DIM + t] = acc;
    rs[t] = acc * a_src[t];
    rd[t] = acc * a_dst[t];
    __syncthreads();
    if (t < HEADS) {
        float s = 0.f, d = 0.f;
        #pragma unroll
        for (int c = 0; c < HID; ++c) { s += rs[t * HID + c]; d += rd[t * HID + c]; }
        ssrc[n * HEADS + t] = s;
        sdst[n * HEADS + t] = d;
    }
}

// ---------------- layer-1 node kernel: gather softmax-aggregate (8 heads),
//                  +b1, ELU, fused lin2 matvec + layer-2 scores ----------------

__global__ __launch_bounds__(256) void l1_kernel(
    const int* __restrict__ row, const int* __restrict__ adj,
    const float* __restrict__ h1, const float* __restrict__ s1, const float* __restrict__ t1,
    const float* __restrict__ b1, const float* __restrict__ W2,
    const float* __restrict__ as2, const float* __restrict__ ad2,
    float* __restrict__ h2, float* __restrict__ s2, float* __restrict__ t2)
{
    int wid = threadIdx.x >> 6, t = threadIdx.x & 63;
    int n = blockIdx.x * 4 + wid;           // grid covers exactly N_NODES
    int beg = row[n], end = row[n + 1];
    int h = t & 7, slot = t >> 3;
    float sd = t1[n * 8 + h];

    // per-head max (8 edge-slots x 8 heads)
    float m = -INFINITY;
    for (int base = beg; base < end; base += 8) {
        int e = base + slot;
        if (e < end) {
            int sv = adj[e];
            float v = lrelu(s1[sv * 8 + h] + sd);
            m = fmaxf(m, v);
        }
    }
    m = fmaxf(m, __shfl_xor(m, 8));
    m = fmaxf(m, __shfl_xor(m, 16));
    m = fmaxf(m, __shfl_xor(m, 32));

    // per-head denom
    float den = 0.f;
    for (int base = beg; base < end; base += 8) {
        int e = base + slot;
        if (e < end) {
            int sv = adj[e];
            float v = lrelu(s1[sv * 8 + h] + sd);
            den += expf(v - m);
        }
    }
    den += __shfl_xor(den, 8);
    den += __shfl_xor(den, 16);
    den += __shfl_xor(den, 32);

    // redistribute per-head (m, den, sd) so lane t gets head t>>3
    int hh = t >> 3;
    float mH  = __shfl(m, hh);     // lane hh holds head hh (slot 0)
    float dH  = __shfl(den, hh);
    float sdH = __shfl(sd, hh);
    float inv = 1.f / (dH + 1e-16f);

    // weighted gather: lane t accumulates channel t (= head t>>3, ch t&7)
    float acc = 0.f;
    for (int e = beg; e < end; ++e) {
        int sv = adj[e];
        float v = lrelu(s1[sv * 8 + hh] + sdH);
        float alpha = expf(v - mH) * inv;
        acc += h1[sv * 64 + t] * alpha;
    }

    // bias + ELU
    float ha = acc + b1[t];
    ha = ha > 0.f ? ha : expm1f(ha);

    // fused lin2: h2[n][t] = sum_k hact[k] * W2[k][t] via shuffle broadcast
    float acc2 = 0.f;
    #pragma unroll 8
    for (int k = 0; k < 64; ++k) {
        acc2 += __shfl(ha, k) * W2[k * 64 + t];
    }
    h2[n * 64 + t] = acc2;

    // layer-2 scores: dot(h2[n], a_src2/a_dst2)
    float rs = acc2 * as2[t], rd = acc2 * ad2[t];
    #pragma unroll
    for (int mk = 32; mk >= 1; mk >>= 1) {
        rs += __shfl_xor(rs, mk);
        rd += __shfl_xor(rd, mk);
    }
    if (t == 0) { s2[n] = rs; t2[n] = rd; }
}

// ---------------- layer-2 node kernel: gather softmax-aggregate (1 head, 64 ch), +b2 ----------------

__global__ __launch_bounds__(256) void l2_kernel(
    const int* __restrict__ row, const int* __restrict__ adj,
    const float* __restrict__ h2, const float* __restrict__ s2, const float* __restrict__ t2,
    const float* __restrict__ b2, float* __restrict__ out)
{
    int wid = threadIdx.x >> 6, t = threadIdx.x & 63;
    int n = blockIdx.x * 4 + wid;
    int beg = row[n], end = row[n + 1];
    float sd = t2[n];

    float m = -INFINITY;
    for (int e = beg + t; e < end; e += 64) {
        int sv = adj[e];
        m = fmaxf(m, lrelu(s2[sv] + sd));
    }
    #pragma unroll
    for (int mk = 32; mk >= 1; mk >>= 1) m = fmaxf(m, __shfl_xor(m, mk));

    float den = 0.f;
    for (int e = beg + t; e < end; e += 64) {
        int sv = adj[e];
        den += expf(lrelu(s2[sv] + sd) - m);
    }
    #pragma unroll
    for (int mk = 32; mk >= 1; mk >>= 1) den += __shfl_xor(den, mk);
    float inv = 1.f / (den + 1e-16f);

    float acc = 0.f;
    for (int e = beg; e < end; ++e) {
        int sv = adj[e];
        float alpha = expf(lrelu(s2[sv] + sd) - m) * inv;
        acc += h2[sv * 64 + t] * alpha;
    }
    out[n * 64 + t] = acc + b2[t];
}

extern "C" void kernel_launch(void* const* d_in, const int* in_sizes, int n_in,
                              void* d_out, int out_size, void* d_ws, size_t ws_size,
                              hipStream_t stream)
{
    const float* x   = (const float*)d_in[0];
    const int* ei    = (const int*)d_in[1];
    const float* W1  = (const float*)d_in[2];
    const float* as1 = (const float*)d_in[3];
    const float* ad1 = (const float*)d_in[4];
    const float* b1  = (const float*)d_in[5];
    const float* W2  = (const float*)d_in[6];
    const float* as2 = (const float*)d_in[7];
    const float* ad2 = (const float*)d_in[8];
    const float* b2  = (const float*)d_in[9];
    float* out = (float*)d_out;

    float* ws = (float*)d_ws;
    float* h1  = ws;                 // N*64
    float* h2  = h1 + N_NODES * 64;  // N*64
    float* s1  = h2 + N_NODES * 64;  // N*8
    float* t1  = s1 + N_NODES * 8;   // N*8
    float* s2  = t1 + N_NODES * 8;   // N
    float* t2  = s2 + N_NODES;       // N
    int*   cnt = (int*)(t2 + N_NODES);   // N  (becomes cursor after scan)
    int*   rowp = cnt + N_NODES;         // N+1
    int*   adj  = rowp + N_NODES + 1;    // ET

    const int B = 256;
    const int EB = (ET + B - 1) / B;

    hipMemsetAsync(cnt, 0, N_NODES * sizeof(int), stream);
    count_kernel<<<EB, B, 0, stream>>>(ei, cnt);
    scan_kernel<<<1, 1024, 0, stream>>>(cnt, rowp);
    fill_kernel<<<EB, B, 0, stream>>>(ei, cnt, adj);

    lin1_kernel<<<N_NODES, 64, 0, stream>>>(x, W1, as1, ad1, h1, s1, t1);

    l1_kernel<<<N_NODES / 4, 256, 0, stream>>>(rowp, adj, h1, s1, t1,
                                               b1, W2, as2, ad2, h2, s2, t2);

    l2_kernel<<<N_NODES / 4, 256, 0, stream>>>(rowp, adj, h2, s2, t2, b2, out);
}

// Round 6
// 429.037 us; speedup vs baseline: 1.7632x; 1.3274x over previous
//
#include <hip/hip_runtime.h>
#include <hip/hip_bf16.h>
#include <math.h>

#define N_NODES 50000
#define N_EDGES 800000
#define ET (N_EDGES + N_NODES)   // edges + self loops
#define IN_DIM 128
#define H1DIM 64                 // HEADS*HID
#define HEADS 8
#define HID 8
#define OUT_DIM 64
#define NEG_SLOPE 0.2f

__device__ __forceinline__ float lrelu(float v) { return v >= 0.f ? v : NEG_SLOPE * v; }

__device__ __forceinline__ float rdlane(float v, int l) {
    return __int_as_float(__builtin_amdgcn_readlane(__float_as_int(v), l));
}

// edge_index is int32 on device (validated round 4)
__device__ __forceinline__ void edge_nodes(const int* __restrict__ ei, int e, int& s, int& d) {
    if (e < N_EDGES) { s = ei[e]; d = ei[N_EDGES + e]; }
    else             { s = e - N_EDGES; d = s; }
}

// ---------------- CSR build (by dst) ----------------

__global__ void count_kernel(const int* __restrict__ ei, int* __restrict__ cnt) {
    int i = blockIdx.x * blockDim.x + threadIdx.x;
    if (i >= ET) return;
    int s, d; edge_nodes(ei, i, s, d);
    atomicAdd(&cnt[d], 1);
}

__global__ __launch_bounds__(1024) void scan_kernel(int* __restrict__ cnt, int* __restrict__ row) {
    __shared__ int part[1024];
    int tid = threadIdx.x;
    const int per = (N_NODES + 1023) / 1024;
    int lo = tid * per, hi = lo + per; if (hi > N_NODES) hi = N_NODES; if (lo > N_NODES) lo = N_NODES;
    int s = 0;
    for (int i = lo; i < hi; ++i) s += cnt[i];
    part[tid] = s;
    __syncthreads();
    for (int off = 1; off < 1024; off <<= 1) {
        int v = part[tid];
        int add = (tid >= off) ? part[tid - off] : 0;
        __syncthreads();
        part[tid] = v + add;
        __syncthreads();
    }
    int off = (tid == 0) ? 0 : part[tid - 1];
    for (int i = lo; i < hi; ++i) {
        int c = cnt[i];
        row[i] = off;
        cnt[i] = off;   // becomes cursor
        off += c;
    }
    if (tid == 1023) row[N_NODES] = part[1023];
}

__global__ void fill_kernel(const int* __restrict__ ei, int* __restrict__ cursor, int* __restrict__ adj) {
    int i = blockIdx.x * blockDim.x + threadIdx.x;
    if (i >= ET) return;
    int s, d; edge_nodes(ei, i, s, d);
    int pos = atomicAdd(&cursor[d], 1);
    adj[pos] = s;
}

// ---------------- lin1: h1 = x @ W1 + per-head scores; 8 nodes/wave ----------------

__global__ __launch_bounds__(256) void lin1_kernel(
    const float* __restrict__ x, const float* __restrict__ W1,
    const float* __restrict__ a_src, const float* __restrict__ a_dst,
    float* __restrict__ h1, float* __restrict__ ssrc, float* __restrict__ sdst)
{
    int wid = threadIdx.x >> 6, t = threadIdx.x & 63;
    int g = blockIdx.x * 4 + wid;          // wave id; 8 nodes per wave
    if (g >= N_NODES / 8) return;          // 6250 waves exactly
    int n0 = g * 8;

    float x0[8], x1[8];
    #pragma unroll
    for (int nn = 0; nn < 8; ++nn) {
        x0[nn] = x[(n0 + nn) * IN_DIM + t];
        x1[nn] = x[(n0 + nn) * IN_DIM + 64 + t];
    }
    float acc[8] = {0,0,0,0,0,0,0,0};
    #pragma unroll 8
    for (int k = 0; k < 64; ++k) {
        float w = W1[k * 64 + t];
        #pragma unroll
        for (int nn = 0; nn < 8; ++nn) acc[nn] += rdlane(x0[nn], k) * w;
    }
    #pragma unroll 8
    for (int k = 0; k < 64; ++k) {
        float w = W1[(k + 64) * 64 + t];
        #pragma unroll
        for (int nn = 0; nn < 8; ++nn) acc[nn] += rdlane(x1[nn], k) * w;
    }

    float av = a_src[t], bv = a_dst[t];
    #pragma unroll
    for (int nn = 0; nn < 8; ++nn) {
        int n = n0 + nn;
        h1[n * 64 + t] = acc[nn];
        float rs = acc[nn] * av, rd = acc[nn] * bv;
        rs += __shfl_xor(rs, 1); rs += __shfl_xor(rs, 2); rs += __shfl_xor(rs, 4);
        rd += __shfl_xor(rd, 1); rd += __shfl_xor(rd, 2); rd += __shfl_xor(rd, 4);
        if ((t & 7) == 0) { ssrc[n * 8 + (t >> 3)] = rs; sdst[n * 8 + (t >> 3)] = rd; }
    }
}

// ---------------- layer-1 node kernel: online softmax gather (8 heads),
//                  +b1, ELU, fused lin2 + layer-2 scores ----------------

__global__ __launch_bounds__(256) void l1_kernel(
    const int* __restrict__ row, const int* __restrict__ adj,
    const float* __restrict__ h1, const float* __restrict__ s1, const float* __restrict__ t1,
    const float* __restrict__ b1, const float* __restrict__ W2,
    const float* __restrict__ as2, const float* __restrict__ ad2,
    float* __restrict__ h2, float* __restrict__ s2, float* __restrict__ t2)
{
    int wid = threadIdx.x >> 6, t = threadIdx.x & 63;
    int n = blockIdx.x * 4 + wid;
    int beg = row[n], end = row[n + 1];
    int slot = t >> 3, h = t & 7;
    float sd = t1[n * 8 + h];

    // single online max+denom pass, 8 edges in parallel (slot dim)
    float m = -3e38f, den = 0.f;
    for (int e = beg + slot; e < end; e += 8) {
        int sv = adj[e];
        float v = lrelu(s1[sv * 8 + h] + sd);
        float mn = fmaxf(m, v);
        den = den * expf(m - mn) + expf(v - mn);
        m = mn;
    }
    #pragma unroll
    for (int mk = 8; mk <= 32; mk <<= 1) {
        float mo = __shfl_xor(m, mk), dn = __shfl_xor(den, mk);
        float mn = fmaxf(m, mo);
        den = den * expf(m - mn) + dn * expf(mo - mn);
        m = mn;
    }
    float inv = 1.f / (den + 1e-16f);

    // slot-parallel aggregate: lane (slot,h) accumulates channels h*8..h*8+7
    float a[8] = {0,0,0,0,0,0,0,0};
    for (int e = beg + slot; e < end; e += 8) {
        int sv = adj[e];
        float v = lrelu(s1[sv * 8 + h] + sd);
        float alpha = expf(v - m) * inv;
        const float4* hp = (const float4*)(h1 + (size_t)sv * 64 + h * 8);
        float4 p0 = hp[0], p1 = hp[1];
        a[0] += p0.x * alpha; a[1] += p0.y * alpha; a[2] += p0.z * alpha; a[3] += p0.w * alpha;
        a[4] += p1.x * alpha; a[5] += p1.y * alpha; a[6] += p1.z * alpha; a[7] += p1.w * alpha;
    }
    #pragma unroll
    for (int mk = 8; mk <= 32; mk <<= 1) {
        #pragma unroll
        for (int j = 0; j < 8; ++j) a[j] += __shfl_xor(a[j], mk);
    }

    // redistribute: lane t needs channel t = head (t>>3), offset (t&7)
    float ha = 0.f;
    #pragma unroll
    for (int j = 0; j < 8; ++j) {
        float v = __shfl(a[j], t >> 3);
        if ((t & 7) == j) ha = v;
    }

    // bias + ELU
    ha += b1[t];
    ha = ha > 0.f ? ha : expm1f(ha);

    // fused lin2
    float acc2 = 0.f;
    #pragma unroll 8
    for (int k = 0; k < 64; ++k) acc2 += __shfl(ha, k) * W2[k * 64 + t];
    h2[n * 64 + t] = acc2;

    // layer-2 scores
    float rs = acc2 * as2[t], rd = acc2 * ad2[t];
    #pragma unroll
    for (int mk = 32; mk >= 1; mk >>= 1) {
        rs += __shfl_xor(rs, mk);
        rd += __shfl_xor(rd, mk);
    }
    if (t == 0) { s2[n] = rs; t2[n] = rd; }
}

// ---------------- layer-2 node kernel ----------------

__global__ __launch_bounds__(256) void l2_kernel(
    const int* __restrict__ row, const int* __restrict__ adj,
    const float* __restrict__ h2, const float* __restrict__ s2, const float* __restrict__ t2,
    const float* __restrict__ b2, float* __restrict__ out)
{
    int wid = threadIdx.x >> 6, t = threadIdx.x & 63;
    int n = blockIdx.x * 4 + wid;
    int beg = row[n], end = row[n + 1];
    int slot = t >> 3, g = t & 7;
    float sd = t2[n];

    // online max+denom: 64 edges in parallel
    float m = -3e38f, den = 0.f;
    for (int e = beg + t; e < end; e += 64) {
        float v = lrelu(s2[adj[e]] + sd);
        float mn = fmaxf(m, v);
        den = den * expf(m - mn) + expf(v - mn);
        m = mn;
    }
    #pragma unroll
    for (int mk = 1; mk <= 32; mk <<= 1) {
        float mo = __shfl_xor(m, mk), dn = __shfl_xor(den, mk);
        float mn = fmaxf(m, mo);
        den = den * expf(m - mn) + dn * expf(mo - mn);
        m = mn;
    }
    float inv = 1.f / (den + 1e-16f);

    // slot-parallel aggregate: lane (slot,g) accumulates channels g*8..g*8+7
    float a[8] = {0,0,0,0,0,0,0,0};
    for (int e = beg + slot; e < end; e += 8) {
        int sv = adj[e];
        float alpha = expf(lrelu(s2[sv] + sd) - m) * inv;
        const float4* hp = (const float4*)(h2 + (size_t)sv * 64 + g * 8);
        float4 p0 = hp[0], p1 = hp[1];
        a[0] += p0.x * alpha; a[1] += p0.y * alpha; a[2] += p0.z * alpha; a[3] += p0.w * alpha;
        a[4] += p1.x * alpha; a[5] += p1.y * alpha; a[6] += p1.z * alpha; a[7] += p1.w * alpha;
    }
    #pragma unroll
    for (int mk = 8; mk <= 32; mk <<= 1) {
        #pragma unroll
        for (int j = 0; j < 8; ++j) a[j] += __shfl_xor(a[j], mk);
    }
    if (slot == 0) {
        float4 o0 = make_float4(a[0] + b2[g * 8 + 0], a[1] + b2[g * 8 + 1],
                                a[2] + b2[g * 8 + 2], a[3] + b2[g * 8 + 3]);
        float4 o1 = make_float4(a[4] + b2[g * 8 + 4], a[5] + b2[g * 8 + 5],
                                a[6] + b2[g * 8 + 6], a[7] + b2[g * 8 + 7]);
        float4* op = (float4*)(out + (size_t)n * 64 + g * 8);
        op[0] = o0; op[1] = o1;
    }
}

extern "C" void kernel_launch(void* const* d_in, const int* in_sizes, int n_in,
                              void* d_out, int out_size, void* d_ws, size_t ws_size,
                              hipStream_t stream)
{
    const float* x   = (const float*)d_in[0];
    const int* ei    = (const int*)d_in[1];
    const float* W1  = (const float*)d_in[2];
    const float* as1 = (const float*)d_in[3];
    const float* ad1 = (const float*)d_in[4];
    const float* b1  = (const float*)d_in[5];
    const float* W2  = (const float*)d_in[6];
    const float* as2 = (const float*)d_in[7];
    const float* ad2 = (const float*)d_in[8];
    const float* b2  = (const float*)d_in[9];
    float* out = (float*)d_out;

    float* ws = (float*)d_ws;
    float* h1  = ws;                 // N*64
    float* h2  = h1 + N_NODES * 64;  // N*64
    float* s1  = h2 + N_NODES * 64;  // N*8
    float* t1  = s1 + N_NODES * 8;   // N*8
    float* s2  = t1 + N_NODES * 8;   // N
    float* t2  = s2 + N_NODES;       // N
    int*   cnt = (int*)(t2 + N_NODES);   // N (becomes cursor)
    int*   rowp = cnt + N_NODES;         // N+1
    int*   adj  = rowp + N_NODES + 1;    // ET

    const int B = 256;
    const int EB = (ET + B - 1) / B;

    hipMemsetAsync(cnt, 0, N_NODES * sizeof(int), stream);
    count_kernel<<<EB, B, 0, stream>>>(ei, cnt);
    scan_kernel<<<1, 1024, 0, stream>>>(cnt, rowp);
    fill_kernel<<<EB, B, 0, stream>>>(ei, cnt, adj);

    lin1_kernel<<<(N_NODES / 8 + 3) / 4, 256, 0, stream>>>(x, W1, as1, ad1, h1, s1, t1);

    l1_kernel<<<N_NODES / 4, 256, 0, stream>>>(rowp, adj, h1, s1, t1,
                                               b1, W2, as2, ad2, h2, s2, t2);

    l2_kernel<<<N_NODES / 4, 256, 0, stream>>>(rowp, adj, h2, s2, t2, b2, out);
}

// Round 7
// 329.229 us; speedup vs baseline: 2.2978x; 1.3032x over previous
//
#include <hip/hip_runtime.h>
#include <hip/hip_bf16.h>
#include <math.h>

#define N_NODES 50000
#define N_EDGES 800000
#define ET (N_EDGES + N_NODES)   // edges + self loops
#define IN_DIM 128
#define H1DIM 64                 // HEADS*HID
#define HEADS 8
#define HID 8
#define OUT_DIM 64
#define NEG_SLOPE 0.2f

#define SCAN_TILE 256
#define NTILES ((N_NODES + SCAN_TILE - 1) / SCAN_TILE)   // 196

__device__ __forceinline__ float lrelu(float v) { return v >= 0.f ? v : NEG_SLOPE * v; }

__device__ __forceinline__ float rdlane(float v, int l) {
    return __int_as_float(__builtin_amdgcn_readlane(__float_as_int(v), l));
}

// edge_index is int32 on device (validated round 4)
__device__ __forceinline__ void edge_nodes(const int* __restrict__ ei, int e, int& s, int& d) {
    if (e < N_EDGES) { s = ei[e]; d = ei[N_EDGES + e]; }
    else             { s = e - N_EDGES; d = s; }
}

// ---------------- CSR build (by dst) ----------------

__global__ void count_kernel(const int* __restrict__ ei, int* __restrict__ cnt) {
    int i = blockIdx.x * blockDim.x + threadIdx.x;
    if (i >= ET) return;
    int s, d; edge_nodes(ei, i, s, d);
    atomicAdd(&cnt[d], 1);
}

// phase A: per-tile LDS scan; row[i] <- tile-exclusive prefix; aux[tile] <- tile total
__global__ __launch_bounds__(SCAN_TILE) void scanA_kernel(
    const int* __restrict__ cnt, int* __restrict__ row, int* __restrict__ aux)
{
    __shared__ int sh[SCAN_TILE];
    int t = threadIdx.x, i = blockIdx.x * SCAN_TILE + t;
    int v = (i < N_NODES) ? cnt[i] : 0;
    sh[t] = v;
    __syncthreads();
    #pragma unroll
    for (int off = 1; off < SCAN_TILE; off <<= 1) {
        int add = (t >= off) ? sh[t - off] : 0;
        __syncthreads();
        sh[t] += add;
        __syncthreads();
    }
    if (i < N_NODES) row[i] = sh[t] - v;           // exclusive within tile
    if (t == SCAN_TILE - 1) aux[blockIdx.x] = sh[t];
}

// phase B: scan the 196 tile totals (single block); also writes row[N_NODES]
__global__ __launch_bounds__(SCAN_TILE) void scanB_kernel(int* __restrict__ aux, int* __restrict__ row) {
    __shared__ int sh[SCAN_TILE];
    int t = threadIdx.x;
    int v = (t < NTILES) ? aux[t] : 0;
    sh[t] = v;
    __syncthreads();
    #pragma unroll
    for (int off = 1; off < SCAN_TILE; off <<= 1) {
        int add = (t >= off) ? sh[t - off] : 0;
        __syncthreads();
        sh[t] += add;
        __syncthreads();
    }
    if (t < NTILES) aux[t] = sh[t] - v;            // exclusive tile offsets
    if (t == NTILES - 1) row[N_NODES] = sh[t];     // grand total = ET
}

// phase C: add tile offset; produce final row + cursor
__global__ __launch_bounds__(SCAN_TILE) void scanC_kernel(
    const int* __restrict__ aux, int* __restrict__ row, int* __restrict__ cursor)
{
    int i = blockIdx.x * SCAN_TILE + threadIdx.x;
    if (i >= N_NODES) return;
    int r = row[i] + aux[i >> 8];
    row[i] = r;
    cursor[i] = r;
}

__global__ void fill_kernel(const int* __restrict__ ei, int* __restrict__ cursor, int* __restrict__ adj) {
    int i = blockIdx.x * blockDim.x + threadIdx.x;
    if (i >= ET) return;
    int s, d; edge_nodes(ei, i, s, d);
    int pos = atomicAdd(&cursor[d], 1);
    adj[pos] = s;
}

// ---------------- lin1: h1 = x @ W1 + per-head scores; 8 nodes/wave ----------------

__global__ __launch_bounds__(256) void lin1_kernel(
    const float* __restrict__ x, const float* __restrict__ W1,
    const float* __restrict__ a_src, const float* __restrict__ a_dst,
    float* __restrict__ h1, float* __restrict__ ssrc, float* __restrict__ sdst)
{
    int wid = threadIdx.x >> 6, t = threadIdx.x & 63;
    int g = blockIdx.x * 4 + wid;          // wave id; 8 nodes per wave
    if (g >= N_NODES / 8) return;          // 6250 waves exactly
    int n0 = g * 8;

    float x0[8], x1[8];
    #pragma unroll
    for (int nn = 0; nn < 8; ++nn) {
        x0[nn] = x[(n0 + nn) * IN_DIM + t];
        x1[nn] = x[(n0 + nn) * IN_DIM + 64 + t];
    }
    float acc[8] = {0,0,0,0,0,0,0,0};
    #pragma unroll 8
    for (int k = 0; k < 64; ++k) {
        float w = W1[k * 64 + t];
        #pragma unroll
        for (int nn = 0; nn < 8; ++nn) acc[nn] += rdlane(x0[nn], k) * w;
    }
    #pragma unroll 8
    for (int k = 0; k < 64; ++k) {
        float w = W1[(k + 64) * 64 + t];
        #pragma unroll
        for (int nn = 0; nn < 8; ++nn) acc[nn] += rdlane(x1[nn], k) * w;
    }

    float av = a_src[t], bv = a_dst[t];
    #pragma unroll
    for (int nn = 0; nn < 8; ++nn) {
        int n = n0 + nn;
        h1[n * 64 + t] = acc[nn];
        float rs = acc[nn] * av, rd = acc[nn] * bv;
        rs += __shfl_xor(rs, 1); rs += __shfl_xor(rs, 2); rs += __shfl_xor(rs, 4);
        rd += __shfl_xor(rd, 1); rd += __shfl_xor(rd, 2); rd += __shfl_xor(rd, 4);
        if ((t & 7) == 0) { ssrc[n * 8 + (t >> 3)] = rs; sdst[n * 8 + (t >> 3)] = rd; }
    }
}

// ---------------- layer-1 node kernel: online softmax gather (8 heads),
//                  +b1, ELU, fused lin2 + layer-2 scores ----------------

__global__ __launch_bounds__(256) void l1_kernel(
    const int* __restrict__ row, const int* __restrict__ adj,
    const float* __restrict__ h1, const float* __restrict__ s1, const float* __restrict__ t1,
    const float* __restrict__ b1, const float* __restrict__ W2,
    const float* __restrict__ as2, const float* __restrict__ ad2,
    float* __restrict__ h2, float* __restrict__ s2, float* __restrict__ t2)
{
    int wid = threadIdx.x >> 6, t = threadIdx.x & 63;
    int n = blockIdx.x * 4 + wid;
    int beg = row[n], end = row[n + 1];
    int slot = t >> 3, h = t & 7;
    float sd = t1[n * 8 + h];

    // single online max+denom pass, 8 edges in parallel (slot dim)
    float m = -3e38f, den = 0.f;
    for (int e = beg + slot; e < end; e += 8) {
        int sv = adj[e];
        float v = lrelu(s1[sv * 8 + h] + sd);
        float mn = fmaxf(m, v);
        den = den * expf(m - mn) + expf(v - mn);
        m = mn;
    }
    #pragma unroll
    for (int mk = 8; mk <= 32; mk <<= 1) {
        float mo = __shfl_xor(m, mk), dn = __shfl_xor(den, mk);
        float mn = fmaxf(m, mo);
        den = den * expf(m - mn) + dn * expf(mo - mn);
        m = mn;
    }
    float inv = 1.f / (den + 1e-16f);

    // slot-parallel aggregate: lane (slot,h) accumulates channels h*8..h*8+7
    float a[8] = {0,0,0,0,0,0,0,0};
    for (int e = beg + slot; e < end; e += 8) {
        int sv = adj[e];
        float v = lrelu(s1[sv * 8 + h] + sd);
        float alpha = expf(v - m) * inv;
        const float4* hp = (const float4*)(h1 + (size_t)sv * 64 + h * 8);
        float4 p0 = hp[0], p1 = hp[1];
        a[0] += p0.x * alpha; a[1] += p0.y * alpha; a[2] += p0.z * alpha; a[3] += p0.w * alpha;
        a[4] += p1.x * alpha; a[5] += p1.y * alpha; a[6] += p1.z * alpha; a[7] += p1.w * alpha;
    }
    #pragma unroll
    for (int mk = 8; mk <= 32; mk <<= 1) {
        #pragma unroll
        for (int j = 0; j < 8; ++j) a[j] += __shfl_xor(a[j], mk);
    }

    // redistribute: lane t needs channel t = head (t>>3), offset (t&7)
    float ha = 0.f;
    #pragma unroll
    for (int j = 0; j < 8; ++j) {
        float v = __shfl(a[j], t >> 3);
        if ((t & 7) == j) ha = v;
    }

    // bias + ELU
    ha += b1[t];
    ha = ha > 0.f ? ha : expm1f(ha);

    // fused lin2
    float acc2 = 0.f;
    #pragma unroll 8
    for (int k = 0; k < 64; ++k) acc2 += __shfl(ha, k) * W2[k * 64 + t];
    h2[n * 64 + t] = acc2;

    // layer-2 scores
    float rs = acc2 * as2[t], rd = acc2 * ad2[t];
    #pragma unroll
    for (int mk = 32; mk >= 1; mk >>= 1) {
        rs += __shfl_xor(rs, mk);
        rd += __shfl_xor(rd, mk);
    }
    if (t == 0) { s2[n] = rs; t2[n] = rd; }
}

// ---------------- layer-2 node kernel ----------------

__global__ __launch_bounds__(256) void l2_kernel(
    const int* __restrict__ row, const int* __restrict__ adj,
    const float* __restrict__ h2, const float* __restrict__ s2, const float* __restrict__ t2,
    const float* __restrict__ b2, float* __restrict__ out)
{
    int wid = threadIdx.x >> 6, t = threadIdx.x & 63;
    int n = blockIdx.x * 4 + wid;
    int beg = row[n], end = row[n + 1];
    int slot = t >> 3, g = t & 7;
    float sd = t2[n];

    // online max+denom: 64 edges in parallel
    float m = -3e38f, den = 0.f;
    for (int e = beg + t; e < end; e += 64) {
        float v = lrelu(s2[adj[e]] + sd);
        float mn = fmaxf(m, v);
        den = den * expf(m - mn) + expf(v - mn);
        m = mn;
    }
    #pragma unroll
    for (int mk = 1; mk <= 32; mk <<= 1) {
        float mo = __shfl_xor(m, mk), dn = __shfl_xor(den, mk);
        float mn = fmaxf(m, mo);
        den = den * expf(m - mn) + dn * expf(mo - mn);
        m = mn;
    }
    float inv = 1.f / (den + 1e-16f);

    // slot-parallel aggregate: lane (slot,g) accumulates channels g*8..g*8+7
    float a[8] = {0,0,0,0,0,0,0,0};
    for (int e = beg + slot; e < end; e += 8) {
        int sv = adj[e];
        float alpha = expf(lrelu(s2[sv] + sd) - m) * inv;
        const float4* hp = (const float4*)(h2 + (size_t)sv * 64 + g * 8);
        float4 p0 = hp[0], p1 = hp[1];
        a[0] += p0.x * alpha; a[1] += p0.y * alpha; a[2] += p0.z * alpha; a[3] += p0.w * alpha;
        a[4] += p1.x * alpha; a[5] += p1.y * alpha; a[6] += p1.z * alpha; a[7] += p1.w * alpha;
    }
    #pragma unroll
    for (int mk = 8; mk <= 32; mk <<= 1) {
        #pragma unroll
        for (int j = 0; j < 8; ++j) a[j] += __shfl_xor(a[j], mk);
    }
    if (slot == 0) {
        float4 o0 = make_float4(a[0] + b2[g * 8 + 0], a[1] + b2[g * 8 + 1],
                                a[2] + b2[g * 8 + 2], a[3] + b2[g * 8 + 3]);
        float4 o1 = make_float4(a[4] + b2[g * 8 + 4], a[5] + b2[g * 8 + 5],
                                a[6] + b2[g * 8 + 6], a[7] + b2[g * 8 + 7]);
        float4* op = (float4*)(out + (size_t)n * 64 + g * 8);
        op[0] = o0; op[1] = o1;
    }
}

extern "C" void kernel_launch(void* const* d_in, const int* in_sizes, int n_in,
                              void* d_out, int out_size, void* d_ws, size_t ws_size,
                              hipStream_t stream)
{
    const float* x   = (const float*)d_in[0];
    const int* ei    = (const int*)d_in[1];
    const float* W1  = (const float*)d_in[2];
    const float* as1 = (const float*)d_in[3];
    const float* ad1 = (const float*)d_in[4];
    const float* b1  = (const float*)d_in[5];
    const float* W2  = (const float*)d_in[6];
    const float* as2 = (const float*)d_in[7];
    const float* ad2 = (const float*)d_in[8];
    const float* b2  = (const float*)d_in[9];
    float* out = (float*)d_out;

    float* ws = (float*)d_ws;
    float* h1  = ws;                 // N*64
    float* h2  = h1 + N_NODES * 64;  // N*64
    float* s1  = h2 + N_NODES * 64;  // N*8
    float* t1  = s1 + N_NODES * 8;   // N*8
    float* s2  = t1 + N_NODES * 8;   // N
    float* t2  = s2 + N_NODES;       // N
    int*   cnt = (int*)(t2 + N_NODES);   // N (becomes cursor)
    int*   rowp = cnt + N_NODES;         // N+1
    int*   aux  = rowp + N_NODES + 1;    // NTILES
    int*   adj  = aux + NTILES;          // ET

    const int B = 256;
    const int EB = (ET + B - 1) / B;

    hipMemsetAsync(cnt, 0, N_NODES * sizeof(int), stream);
    count_kernel<<<EB, B, 0, stream>>>(ei, cnt);
    scanA_kernel<<<NTILES, SCAN_TILE, 0, stream>>>(cnt, rowp, aux);
    scanB_kernel<<<1, SCAN_TILE, 0, stream>>>(aux, rowp);
    scanC_kernel<<<NTILES, SCAN_TILE, 0, stream>>>(aux, rowp, cnt);
    fill_kernel<<<EB, B, 0, stream>>>(ei, cnt, adj);

    lin1_kernel<<<(N_NODES / 8 + 3) / 4, 256, 0, stream>>>(x, W1, as1, ad1, h1, s1, t1);

    l1_kernel<<<N_NODES / 4, 256, 0, stream>>>(rowp, adj, h1, s1, t1,
                                               b1, W2, as2, ad2, h2, s2, t2);

    l2_kernel<<<N_NODES / 4, 256, 0, stream>>>(rowp, adj, h2, s2, t2, b2, out);
}

// Round 8
// 327.607 us; speedup vs baseline: 2.3092x; 1.0050x over previous
//
#include <hip/hip_runtime.h>
#include <hip/hip_bf16.h>
#include <math.h>

#define N_NODES 50000
#define N_EDGES 800000
#define ET (N_EDGES + N_NODES)   // edges + self loops
#define IN_DIM 128
#define H1DIM 64                 // HEADS*HID
#define HEADS 8
#define HID 8
#define OUT_DIM 64
#define NEG_SLOPE 0.2f

#define SCAN_TILE 256
#define NTILES ((N_NODES + SCAN_TILE - 1) / SCAN_TILE)   // 196
#define RC 8                      // cached edge-iterations per lane (deg <= 57+slot)

__device__ __forceinline__ float lrelu(float v) { return v >= 0.f ? v : NEG_SLOPE * v; }

__device__ __forceinline__ float rdlane(float v, int l) {
    return __int_as_float(__builtin_amdgcn_readlane(__float_as_int(v), l));
}

// edge_index is int32 on device (validated round 4)
__device__ __forceinline__ void edge_nodes(const int* __restrict__ ei, int e, int& s, int& d) {
    if (e < N_EDGES) { s = ei[e]; d = ei[N_EDGES + e]; }
    else             { s = e - N_EDGES; d = s; }
}

// ---------------- CSR build (by dst) ----------------

__global__ void count_kernel(const int* __restrict__ ei, int* __restrict__ cnt) {
    int i = blockIdx.x * blockDim.x + threadIdx.x;
    if (i >= ET) return;
    int s, d; edge_nodes(ei, i, s, d);
    atomicAdd(&cnt[d], 1);
}

// phase A: per-tile LDS scan; row[i] <- tile-exclusive prefix; aux[tile] <- tile total
__global__ __launch_bounds__(SCAN_TILE) void scanA_kernel(
    const int* __restrict__ cnt, int* __restrict__ row, int* __restrict__ aux)
{
    __shared__ int sh[SCAN_TILE];
    int t = threadIdx.x, i = blockIdx.x * SCAN_TILE + t;
    int v = (i < N_NODES) ? cnt[i] : 0;
    sh[t] = v;
    __syncthreads();
    #pragma unroll
    for (int off = 1; off < SCAN_TILE; off <<= 1) {
        int add = (t >= off) ? sh[t - off] : 0;
        __syncthreads();
        sh[t] += add;
        __syncthreads();
    }
    if (i < N_NODES) row[i] = sh[t] - v;           // exclusive within tile
    if (t == SCAN_TILE - 1) aux[blockIdx.x] = sh[t];
}

// phase B: scan the tile totals (single block); also writes row[N_NODES]
__global__ __launch_bounds__(SCAN_TILE) void scanB_kernel(int* __restrict__ aux, int* __restrict__ row) {
    __shared__ int sh[SCAN_TILE];
    int t = threadIdx.x;
    int v = (t < NTILES) ? aux[t] : 0;
    sh[t] = v;
    __syncthreads();
    #pragma unroll
    for (int off = 1; off < SCAN_TILE; off <<= 1) {
        int add = (t >= off) ? sh[t - off] : 0;
        __syncthreads();
        sh[t] += add;
        __syncthreads();
    }
    if (t < NTILES) aux[t] = sh[t] - v;            // exclusive tile offsets
    if (t == NTILES - 1) row[N_NODES] = sh[t];     // grand total = ET
}

// phase C: add tile offset; produce final row + cursor
__global__ __launch_bounds__(SCAN_TILE) void scanC_kernel(
    const int* __restrict__ aux, int* __restrict__ row, int* __restrict__ cursor)
{
    int i = blockIdx.x * SCAN_TILE + threadIdx.x;
    if (i >= N_NODES) return;
    int r = row[i] + aux[i >> 8];
    row[i] = r;
    cursor[i] = r;
}

__global__ void fill_kernel(const int* __restrict__ ei, int* __restrict__ cursor, int* __restrict__ adj) {
    int i = blockIdx.x * blockDim.x + threadIdx.x;
    if (i >= ET) return;
    int s, d; edge_nodes(ei, i, s, d);
    int pos = atomicAdd(&cursor[d], 1);
    adj[pos] = s;
}

// ---------------- lin1: h1 = x @ W1 + per-head scores; 8 nodes/wave ----------------

__global__ __launch_bounds__(256) void lin1_kernel(
    const float* __restrict__ x, const float* __restrict__ W1,
    const float* __restrict__ a_src, const float* __restrict__ a_dst,
    float* __restrict__ h1, float* __restrict__ ssrc, float* __restrict__ sdst)
{
    int wid = threadIdx.x >> 6, t = threadIdx.x & 63;
    int g = blockIdx.x * 4 + wid;          // wave id; 8 nodes per wave
    if (g >= N_NODES / 8) return;          // 6250 waves exactly
    int n0 = g * 8;

    float x0[8], x1[8];
    #pragma unroll
    for (int nn = 0; nn < 8; ++nn) {
        x0[nn] = x[(n0 + nn) * IN_DIM + t];
        x1[nn] = x[(n0 + nn) * IN_DIM + 64 + t];
    }
    float acc[8] = {0,0,0,0,0,0,0,0};
    #pragma unroll 8
    for (int k = 0; k < 64; ++k) {
        float w = W1[k * 64 + t];
        #pragma unroll
        for (int nn = 0; nn < 8; ++nn) acc[nn] += rdlane(x0[nn], k) * w;
    }
    #pragma unroll 8
    for (int k = 0; k < 64; ++k) {
        float w = W1[(k + 64) * 64 + t];
        #pragma unroll
        for (int nn = 0; nn < 8; ++nn) acc[nn] += rdlane(x1[nn], k) * w;
    }

    float av = a_src[t], bv = a_dst[t];
    #pragma unroll
    for (int nn = 0; nn < 8; ++nn) {
        int n = n0 + nn;
        h1[n * 64 + t] = acc[nn];
        float rs = acc[nn] * av, rd = acc[nn] * bv;
        rs += __shfl_xor(rs, 1); rs += __shfl_xor(rs, 2); rs += __shfl_xor(rs, 4);
        rd += __shfl_xor(rd, 1); rd += __shfl_xor(rd, 2); rd += __shfl_xor(rd, 4);
        if ((t & 7) == 0) { ssrc[n * 8 + (t >> 3)] = rs; sdst[n * 8 + (t >> 3)] = rd; }
    }
}

// ---------------- layer-1 node kernel: register-cached softmax gather (8 heads),
//                  +b1, ELU, fused lin2 + layer-2 scores ----------------

__global__ __launch_bounds__(256) void l1_kernel(
    const int* __restrict__ row, const int* __restrict__ adj,
    const float* __restrict__ h1, const float* __restrict__ s1, const float* __restrict__ t1,
    const float* __restrict__ b1, const float* __restrict__ W2,
    const float* __restrict__ as2, const float* __restrict__ ad2,
    float* __restrict__ h2, float* __restrict__ s2, float* __restrict__ t2)
{
    int wid = threadIdx.x >> 6, t = threadIdx.x & 63;
    int n = blockIdx.x * 4 + wid;
    int beg = row[n], end = row[n + 1];
    int slot = t >> 3, h = t & 7;
    float sd = t1[n * 8 + h];
    const int e0 = beg + slot;

    // single gather pass: cache (sv, score) per lane
    int   sv[RC];
    float p[RC];
    float m = -3e38f;
    #pragma unroll
    for (int it = 0; it < RC; ++it) {
        int e = e0 + it * 8;
        bool ok = e < end;
        int s = ok ? adj[e] : n;
        sv[it] = s;
        float v = ok ? lrelu(s1[s * 8 + h] + sd) : -3e38f;
        p[it] = v;
        m = fmaxf(m, v);
    }
    for (int e = e0 + RC * 8; e < end; e += 8)      // improbable tail
        m = fmaxf(m, lrelu(s1[adj[e] * 8 + h] + sd));
    m = fmaxf(m, __shfl_xor(m, 8));
    m = fmaxf(m, __shfl_xor(m, 16));
    m = fmaxf(m, __shfl_xor(m, 32));

    float den = 0.f;
    #pragma unroll
    for (int it = 0; it < RC; ++it) {
        float pe = __expf(p[it] - m);               // empty slots -> exp(-huge) = 0
        p[it] = pe;
        den += pe;
    }
    for (int e = e0 + RC * 8; e < end; e += 8)
        den += __expf(lrelu(s1[adj[e] * 8 + h] + sd) - m);
    den += __shfl_xor(den, 8);
    den += __shfl_xor(den, 16);
    den += __shfl_xor(den, 32);
    float inv = 1.f / (den + 1e-16f);

    // aggregate from cache: lane (slot,h) accumulates channels h*8..h*8+7
    float a[8] = {0,0,0,0,0,0,0,0};
    #pragma unroll
    for (int it = 0; it < RC; ++it) {
        int e = e0 + it * 8;
        if (e < end) {
            float alpha = p[it] * inv;
            const float4* hp = (const float4*)(h1 + (size_t)sv[it] * 64 + h * 8);
            float4 p0 = hp[0], p1 = hp[1];
            a[0] += p0.x * alpha; a[1] += p0.y * alpha; a[2] += p0.z * alpha; a[3] += p0.w * alpha;
            a[4] += p1.x * alpha; a[5] += p1.y * alpha; a[6] += p1.z * alpha; a[7] += p1.w * alpha;
        }
    }
    for (int e = e0 + RC * 8; e < end; e += 8) {
        int s = adj[e];
        float alpha = __expf(lrelu(s1[s * 8 + h] + sd) - m) * inv;
        const float4* hp = (const float4*)(h1 + (size_t)s * 64 + h * 8);
        float4 p0 = hp[0], p1 = hp[1];
        a[0] += p0.x * alpha; a[1] += p0.y * alpha; a[2] += p0.z * alpha; a[3] += p0.w * alpha;
        a[4] += p1.x * alpha; a[5] += p1.y * alpha; a[6] += p1.z * alpha; a[7] += p1.w * alpha;
    }
    #pragma unroll
    for (int mk = 8; mk <= 32; mk <<= 1) {
        #pragma unroll
        for (int j = 0; j < 8; ++j) a[j] += __shfl_xor(a[j], mk);
    }

    // redistribute: lane t needs channel t = head (t>>3), offset (t&7)
    float ha = 0.f;
    #pragma unroll
    for (int j = 0; j < 8; ++j) {
        float v = __shfl(a[j], t >> 3);
        if ((t & 7) == j) ha = v;
    }

    // bias + ELU (fast exp; abs err ~1e-7 << 0.068 threshold)
    ha += b1[t];
    ha = ha > 0.f ? ha : (__expf(ha) - 1.f);

    // fused lin2
    float acc2 = 0.f;
    #pragma unroll 8
    for (int k = 0; k < 64; ++k) acc2 += __shfl(ha, k) * W2[k * 64 + t];
    h2[n * 64 + t] = acc2;

    // layer-2 scores
    float rs = acc2 * as2[t], rd = acc2 * ad2[t];
    #pragma unroll
    for (int mk = 32; mk >= 1; mk >>= 1) {
        rs += __shfl_xor(rs, mk);
        rd += __shfl_xor(rd, mk);
    }
    if (t == 0) { s2[n] = rs; t2[n] = rd; }
}

// ---------------- layer-2 node kernel: register-cached softmax gather (1 head, 64 ch) ----------------

__global__ __launch_bounds__(256) void l2_kernel(
    const int* __restrict__ row, const int* __restrict__ adj,
    const float* __restrict__ h2, const float* __restrict__ s2, const float* __restrict__ t2,
    const float* __restrict__ b2, float* __restrict__ out)
{
    int wid = threadIdx.x >> 6, t = threadIdx.x & 63;
    int n = blockIdx.x * 4 + wid;
    int beg = row[n], end = row[n + 1];
    int slot = t >> 3, g = t & 7;
    float sd = t2[n];
    const int e0 = beg + slot;

    // single gather pass (redundant across the 8 g-lanes of a slot: same addresses, broadcast)
    int   sv[RC];
    float p[RC];
    float m = -3e38f;
    #pragma unroll
    for (int it = 0; it < RC; ++it) {
        int e = e0 + it * 8;
        bool ok = e < end;
        int s = ok ? adj[e] : n;
        sv[it] = s;
        float v = ok ? lrelu(s2[s] + sd) : -3e38f;
        p[it] = v;
        m = fmaxf(m, v);
    }
    for (int e = e0 + RC * 8; e < end; e += 8)
        m = fmaxf(m, lrelu(s2[adj[e]] + sd));
    m = fmaxf(m, __shfl_xor(m, 8));
    m = fmaxf(m, __shfl_xor(m, 16));
    m = fmaxf(m, __shfl_xor(m, 32));

    float den = 0.f;
    #pragma unroll
    for (int it = 0; it < RC; ++it) {
        float pe = __expf(p[it] - m);
        p[it] = pe;
        den += pe;
    }
    for (int e = e0 + RC * 8; e < end; e += 8)
        den += __expf(lrelu(s2[adj[e]] + sd) - m);
    den += __shfl_xor(den, 8);
    den += __shfl_xor(den, 16);
    den += __shfl_xor(den, 32);
    float inv = 1.f / (den + 1e-16f);

    // aggregate: lane (slot,g) accumulates channels g*8..g*8+7
    float a[8] = {0,0,0,0,0,0,0,0};
    #pragma unroll
    for (int it = 0; it < RC; ++it) {
        int e = e0 + it * 8;
        if (e < end) {
            float alpha = p[it] * inv;
            const float4* hp = (const float4*)(h2 + (size_t)sv[it] * 64 + g * 8);
            float4 p0 = hp[0], p1 = hp[1];
            a[0] += p0.x * alpha; a[1] += p0.y * alpha; a[2] += p0.z * alpha; a[3] += p0.w * alpha;
            a[4] += p1.x * alpha; a[5] += p1.y * alpha; a[6] += p1.z * alpha; a[7] += p1.w * alpha;
        }
    }
    for (int e = e0 + RC * 8; e < end; e += 8) {
        int s = adj[e];
        float alpha = __expf(lrelu(s2[s] + sd) - m) * inv;
        const float4* hp = (const float4*)(h2 + (size_t)s * 64 + g * 8);
        float4 p0 = hp[0], p1 = hp[1];
        a[0] += p0.x * alpha; a[1] += p0.y * alpha; a[2] += p0.z * alpha; a[3] += p0.w * alpha;
        a[4] += p1.x * alpha; a[5] += p1.y * alpha; a[6] += p1.z * alpha; a[7] += p1.w * alpha;
    }
    #pragma unroll
    for (int mk = 8; mk <= 32; mk <<= 1) {
        #pragma unroll
        for (int j = 0; j < 8; ++j) a[j] += __shfl_xor(a[j], mk);
    }
    if (slot == 0) {
        float4 o0 = make_float4(a[0] + b2[g * 8 + 0], a[1] + b2[g * 8 + 1],
                                a[2] + b2[g * 8 + 2], a[3] + b2[g * 8 + 3]);
        float4 o1 = make_float4(a[4] + b2[g * 8 + 4], a[5] + b2[g * 8 + 5],
                                a[6] + b2[g * 8 + 6], a[7] + b2[g * 8 + 7]);
        float4* op = (float4*)(out + (size_t)n * 64 + g * 8);
        op[0] = o0; op[1] = o1;
    }
}

extern "C" void kernel_launch(void* const* d_in, const int* in_sizes, int n_in,
                              void* d_out, int out_size, void* d_ws, size_t ws_size,
                              hipStream_t stream)
{
    const float* x   = (const float*)d_in[0];
    const int* ei    = (const int*)d_in[1];
    const float* W1  = (const float*)d_in[2];
    const float* as1 = (const float*)d_in[3];
    const float* ad1 = (const float*)d_in[4];
    const float* b1  = (const float*)d_in[5];
    const float* W2  = (const float*)d_in[6];
    const float* as2 = (const float*)d_in[7];
    const float* ad2 = (const float*)d_in[8];
    const float* b2  = (const float*)d_in[9];
    float* out = (float*)d_out;

    float* ws = (float*)d_ws;
    float* h1  = ws;                 // N*64
    float* h2  = h1 + N_NODES * 64;  // N*64
    float* s1  = h2 + N_NODES * 64;  // N*8
    float* t1  = s1 + N_NODES * 8;   // N*8
    float* s2  = t1 + N_NODES * 8;   // N
    float* t2  = s2 + N_NODES;       // N
    int*   cnt = (int*)(t2 + N_NODES);   // N (becomes cursor)
    int*   rowp = cnt + N_NODES;         // N+1
    int*   aux  = rowp + N_NODES + 1;    // NTILES
    int*   adj  = aux + NTILES;          // ET

    const int B = 256;
    const int EB = (ET + B - 1) / B;

    hipMemsetAsync(cnt, 0, N_NODES * sizeof(int), stream);
    count_kernel<<<EB, B, 0, stream>>>(ei, cnt);
    scanA_kernel<<<NTILES, SCAN_TILE, 0, stream>>>(cnt, rowp, aux);
    scanB_kernel<<<1, SCAN_TILE, 0, stream>>>(aux, rowp);
    scanC_kernel<<<NTILES, SCAN_TILE, 0, stream>>>(aux, rowp, cnt);
    fill_kernel<<<EB, B, 0, stream>>>(ei, cnt, adj);

    lin1_kernel<<<(N_NODES / 8 + 3) / 4, 256, 0, stream>>>(x, W1, as1, ad1, h1, s1, t1);

    l1_kernel<<<N_NODES / 4, 256, 0, stream>>>(rowp, adj, h1, s1, t1,
                                               b1, W2, as2, ad2, h2, s2, t2);

    l2_kernel<<<N_NODES / 4, 256, 0, stream>>>(rowp, adj, h2, s2, t2, b2, out);
}

// Round 9
// 322.693 us; speedup vs baseline: 2.3443x; 1.0152x over previous
//
#include <hip/hip_runtime.h>
#include <hip/hip_fp16.h>
#include <math.h>

#define N_NODES 50000
#define N_EDGES 800000
#define ET (N_EDGES + N_NODES)   // edges + self loops
#define IN_DIM 128
#define H1DIM 64                 // HEADS*HID
#define HEADS 8
#define HID 8
#define OUT_DIM 64
#define NEG_SLOPE 0.2f

#define SCAN_TILE 256
#define NTILES ((N_NODES + SCAN_TILE - 1) / SCAN_TILE)   // 196
#define RC 8                      // cached edge-iterations per lane (deg <= 57+slot)

__device__ __forceinline__ float lrelu(float v) { return v >= 0.f ? v : NEG_SLOPE * v; }

__device__ __forceinline__ float rdlane(float v, int l) {
    return __int_as_float(__builtin_amdgcn_readlane(__float_as_int(v), l));
}

// unpack 8 fp16 (16B) and FMA into a[8]
__device__ __forceinline__ void fma8h(const __half* __restrict__ base, float alpha, float* a) {
    uint4 u = *reinterpret_cast<const uint4*>(base);
    float2 f0 = __half22float2(*(const __half2*)&u.x);
    float2 f1 = __half22float2(*(const __half2*)&u.y);
    float2 f2 = __half22float2(*(const __half2*)&u.z);
    float2 f3 = __half22float2(*(const __half2*)&u.w);
    a[0] += f0.x * alpha; a[1] += f0.y * alpha;
    a[2] += f1.x * alpha; a[3] += f1.y * alpha;
    a[4] += f2.x * alpha; a[5] += f2.y * alpha;
    a[6] += f3.x * alpha; a[7] += f3.y * alpha;
}

// edge_index is int32 on device (validated round 4)
__device__ __forceinline__ void edge_nodes(const int* __restrict__ ei, int e, int& s, int& d) {
    if (e < N_EDGES) { s = ei[e]; d = ei[N_EDGES + e]; }
    else             { s = e - N_EDGES; d = s; }
}

// ---------------- CSR build (by dst) ----------------

__global__ void count_kernel(const int* __restrict__ ei, int* __restrict__ cnt) {
    int i = blockIdx.x * blockDim.x + threadIdx.x;
    if (i >= ET) return;
    int s, d; edge_nodes(ei, i, s, d);
    atomicAdd(&cnt[d], 1);
}

__global__ __launch_bounds__(SCAN_TILE) void scanA_kernel(
    const int* __restrict__ cnt, int* __restrict__ row, int* __restrict__ aux)
{
    __shared__ int sh[SCAN_TILE];
    int t = threadIdx.x, i = blockIdx.x * SCAN_TILE + t;
    int v = (i < N_NODES) ? cnt[i] : 0;
    sh[t] = v;
    __syncthreads();
    #pragma unroll
    for (int off = 1; off < SCAN_TILE; off <<= 1) {
        int add = (t >= off) ? sh[t - off] : 0;
        __syncthreads();
        sh[t] += add;
        __syncthreads();
    }
    if (i < N_NODES) row[i] = sh[t] - v;           // exclusive within tile
    if (t == SCAN_TILE - 1) aux[blockIdx.x] = sh[t];
}

__global__ __launch_bounds__(SCAN_TILE) void scanB_kernel(int* __restrict__ aux, int* __restrict__ row) {
    __shared__ int sh[SCAN_TILE];
    int t = threadIdx.x;
    int v = (t < NTILES) ? aux[t] : 0;
    sh[t] = v;
    __syncthreads();
    #pragma unroll
    for (int off = 1; off < SCAN_TILE; off <<= 1) {
        int add = (t >= off) ? sh[t - off] : 0;
        __syncthreads();
        sh[t] += add;
        __syncthreads();
    }
    if (t < NTILES) aux[t] = sh[t] - v;            // exclusive tile offsets
    if (t == NTILES - 1) row[N_NODES] = sh[t];     // grand total = ET
}

__global__ __launch_bounds__(SCAN_TILE) void scanC_kernel(
    const int* __restrict__ aux, int* __restrict__ row, int* __restrict__ cursor)
{
    int i = blockIdx.x * SCAN_TILE + threadIdx.x;
    if (i >= N_NODES) return;
    int r = row[i] + aux[i >> 8];
    row[i] = r;
    cursor[i] = r;
}

__global__ void fill_kernel(const int* __restrict__ ei, int* __restrict__ cursor, int* __restrict__ adj) {
    int i = blockIdx.x * blockDim.x + threadIdx.x;
    if (i >= ET) return;
    int s, d; edge_nodes(ei, i, s, d);
    int pos = atomicAdd(&cursor[d], 1);
    adj[pos] = s;
}

// ---------------- lin1: h1 = x @ W1 + per-head scores; 8 nodes/wave ----------------

__global__ __launch_bounds__(256) void lin1_kernel(
    const float* __restrict__ x, const float* __restrict__ W1,
    const float* __restrict__ a_src, const float* __restrict__ a_dst,
    __half* __restrict__ h1, float* __restrict__ ssrc, float* __restrict__ sdst)
{
    int wid = threadIdx.x >> 6, t = threadIdx.x & 63;
    int g = blockIdx.x * 4 + wid;          // wave id; 8 nodes per wave
    if (g >= N_NODES / 8) return;          // 6250 waves exactly
    int n0 = g * 8;

    float x0[8], x1[8];
    #pragma unroll
    for (int nn = 0; nn < 8; ++nn) {
        x0[nn] = x[(n0 + nn) * IN_DIM + t];
        x1[nn] = x[(n0 + nn) * IN_DIM + 64 + t];
    }
    float acc[8] = {0,0,0,0,0,0,0,0};
    #pragma unroll 8
    for (int k = 0; k < 64; ++k) {
        float w = W1[k * 64 + t];
        #pragma unroll
        for (int nn = 0; nn < 8; ++nn) acc[nn] += rdlane(x0[nn], k) * w;
    }
    #pragma unroll 8
    for (int k = 0; k < 64; ++k) {
        float w = W1[(k + 64) * 64 + t];
        #pragma unroll
        for (int nn = 0; nn < 8; ++nn) acc[nn] += rdlane(x1[nn], k) * w;
    }

    float av = a_src[t], bv = a_dst[t];
    #pragma unroll
    for (int nn = 0; nn < 8; ++nn) {
        int n = n0 + nn;
        h1[n * 64 + t] = __float2half(acc[nn]);
        float rs = acc[nn] * av, rd = acc[nn] * bv;
        rs += __shfl_xor(rs, 1); rs += __shfl_xor(rs, 2); rs += __shfl_xor(rs, 4);
        rd += __shfl_xor(rd, 1); rd += __shfl_xor(rd, 2); rd += __shfl_xor(rd, 4);
        if ((t & 7) == 0) { ssrc[n * 8 + (t >> 3)] = rs; sdst[n * 8 + (t >> 3)] = rd; }
    }
}

// ---------------- layer-1 node kernel ----------------

__global__ __launch_bounds__(256) void l1_kernel(
    const int* __restrict__ row, const int* __restrict__ adj,
    const __half* __restrict__ h1, const float* __restrict__ s1, const float* __restrict__ t1,
    const float* __restrict__ b1, const float* __restrict__ W2,
    const float* __restrict__ as2, const float* __restrict__ ad2,
    __half* __restrict__ h2, float* __restrict__ s2, float* __restrict__ t2)
{
    int wid = threadIdx.x >> 6, t = threadIdx.x & 63;
    int n = blockIdx.x * 4 + wid;
    int beg = row[n], end = row[n + 1];
    int slot = t >> 3, h = t & 7;
    float sd = t1[n * 8 + h];
    const int e0 = beg + slot;

    // single gather pass: cache (sv, score) per lane
    int   sv[RC];
    float p[RC];
    float m = -3e38f;
    #pragma unroll
    for (int it = 0; it < RC; ++it) {
        int e = e0 + it * 8;
        bool ok = e < end;
        int s = ok ? adj[e] : n;
        sv[it] = s;
        float v = ok ? lrelu(s1[s * 8 + h] + sd) : -3e38f;
        p[it] = v;
        m = fmaxf(m, v);
    }
    for (int e = e0 + RC * 8; e < end; e += 8)      // improbable tail
        m = fmaxf(m, lrelu(s1[adj[e] * 8 + h] + sd));
    m = fmaxf(m, __shfl_xor(m, 8));
    m = fmaxf(m, __shfl_xor(m, 16));
    m = fmaxf(m, __shfl_xor(m, 32));

    float den = 0.f;
    #pragma unroll
    for (int it = 0; it < RC; ++it) {
        float pe = __expf(p[it] - m);               // empty slots -> 0
        p[it] = pe;
        den += pe;
    }
    for (int e = e0 + RC * 8; e < end; e += 8)
        den += __expf(lrelu(s1[adj[e] * 8 + h] + sd) - m);
    den += __shfl_xor(den, 8);
    den += __shfl_xor(den, 16);
    den += __shfl_xor(den, 32);
    float inv = 1.f / (den + 1e-16f);

    // aggregate from cache: lane (slot,h) accumulates channels h*8..h*8+7
    float a[8] = {0,0,0,0,0,0,0,0};
    #pragma unroll
    for (int it = 0; it < RC; ++it) {
        int e = e0 + it * 8;
        if (e < end) fma8h(h1 + (size_t)sv[it] * 64 + h * 8, p[it] * inv, a);
    }
    for (int e = e0 + RC * 8; e < end; e += 8) {
        int s = adj[e];
        float alpha = __expf(lrelu(s1[s * 8 + h] + sd) - m) * inv;
        fma8h(h1 + (size_t)s * 64 + h * 8, alpha, a);
    }
    #pragma unroll
    for (int mk = 8; mk <= 32; mk <<= 1) {
        #pragma unroll
        for (int j = 0; j < 8; ++j) a[j] += __shfl_xor(a[j], mk);
    }

    // redistribute: lane t needs channel t = head (t>>3), offset (t&7)
    float ha = 0.f;
    #pragma unroll
    for (int j = 0; j < 8; ++j) {
        float v = __shfl(a[j], t >> 3);
        if ((t & 7) == j) ha = v;
    }

    // bias + ELU
    ha += b1[t];
    ha = ha > 0.f ? ha : (__expf(ha) - 1.f);

    // fused lin2
    float acc2 = 0.f;
    #pragma unroll 8
    for (int k = 0; k < 64; ++k) acc2 += __shfl(ha, k) * W2[k * 64 + t];
    h2[n * 64 + t] = __float2half(acc2);

    // layer-2 scores
    float rs = acc2 * as2[t], rd = acc2 * ad2[t];
    #pragma unroll
    for (int mk = 32; mk >= 1; mk >>= 1) {
        rs += __shfl_xor(rs, mk);
        rd += __shfl_xor(rd, mk);
    }
    if (t == 0) { s2[n] = rs; t2[n] = rd; }
}

// ---------------- layer-2 node kernel ----------------

__global__ __launch_bounds__(256) void l2_kernel(
    const int* __restrict__ row, const int* __restrict__ adj,
    const __half* __restrict__ h2, const float* __restrict__ s2, const float* __restrict__ t2,
    const float* __restrict__ b2, float* __restrict__ out)
{
    int wid = threadIdx.x >> 6, t = threadIdx.x & 63;
    int n = blockIdx.x * 4 + wid;
    int beg = row[n], end = row[n + 1];
    int slot = t >> 3, g = t & 7;
    float sd = t2[n];
    const int e0 = beg + slot;

    int   sv[RC];
    float p[RC];
    float m = -3e38f;
    #pragma unroll
    for (int it = 0; it < RC; ++it) {
        int e = e0 + it * 8;
        bool ok = e < end;
        int s = ok ? adj[e] : n;
        sv[it] = s;
        float v = ok ? lrelu(s2[s] + sd) : -3e38f;
        p[it] = v;
        m = fmaxf(m, v);
    }
    for (int e = e0 + RC * 8; e < end; e += 8)
        m = fmaxf(m, lrelu(s2[adj[e]] + sd));
    m = fmaxf(m, __shfl_xor(m, 8));
    m = fmaxf(m, __shfl_xor(m, 16));
    m = fmaxf(m, __shfl_xor(m, 32));

    float den = 0.f;
    #pragma unroll
    for (int it = 0; it < RC; ++it) {
        float pe = __expf(p[it] - m);
        p[it] = pe;
        den += pe;
    }
    for (int e = e0 + RC * 8; e < end; e += 8)
        den += __expf(lrelu(s2[adj[e]] + sd) - m);
    den += __shfl_xor(den, 8);
    den += __shfl_xor(den, 16);
    den += __shfl_xor(den, 32);
    float inv = 1.f / (den + 1e-16f);

    float a[8] = {0,0,0,0,0,0,0,0};
    #pragma unroll
    for (int it = 0; it < RC; ++it) {
        int e = e0 + it * 8;
        if (e < end) fma8h(h2 + (size_t)sv[it] * 64 + g * 8, p[it] * inv, a);
    }
    for (int e = e0 + RC * 8; e < end; e += 8) {
        int s = adj[e];
        float alpha = __expf(lrelu(s2[s] + sd) - m) * inv;
        fma8h(h2 + (size_t)s * 64 + g * 8, alpha, a);
    }
    #pragma unroll
    for (int mk = 8; mk <= 32; mk <<= 1) {
        #pragma unroll
        for (int j = 0; j < 8; ++j) a[j] += __shfl_xor(a[j], mk);
    }
    if (slot == 0) {
        float4 o0 = make_float4(a[0] + b2[g * 8 + 0], a[1] + b2[g * 8 + 1],
                                a[2] + b2[g * 8 + 2], a[3] + b2[g * 8 + 3]);
        float4 o1 = make_float4(a[4] + b2[g * 8 + 4], a[5] + b2[g * 8 + 5],
                                a[6] + b2[g * 8 + 6], a[7] + b2[g * 8 + 7]);
        float4* op = (float4*)(out + (size_t)n * 64 + g * 8);
        op[0] = o0; op[1] = o1;
    }
}

extern "C" void kernel_launch(void* const* d_in, const int* in_sizes, int n_in,
                              void* d_out, int out_size, void* d_ws, size_t ws_size,
                              hipStream_t stream)
{
    const float* x   = (const float*)d_in[0];
    const int* ei    = (const int*)d_in[1];
    const float* W1  = (const float*)d_in[2];
    const float* as1 = (const float*)d_in[3];
    const float* ad1 = (const float*)d_in[4];
    const float* b1  = (const float*)d_in[5];
    const float* W2  = (const float*)d_in[6];
    const float* as2 = (const float*)d_in[7];
    const float* ad2 = (const float*)d_in[8];
    const float* b2  = (const float*)d_in[9];
    float* out = (float*)d_out;

    char* wsb = (char*)d_ws;
    __half* h1  = (__half*)wsb;                       // N*64 fp16
    __half* h2  = h1 + (size_t)N_NODES * 64;          // N*64 fp16
    float*  s1  = (float*)(h2 + (size_t)N_NODES * 64);// N*8
    float*  t1  = s1 + N_NODES * 8;                   // N*8
    float*  s2  = t1 + N_NODES * 8;                   // N
    float*  t2  = s2 + N_NODES;                       // N
    int*    cnt = (int*)(t2 + N_NODES);               // N (becomes cursor)
    int*    rowp = cnt + N_NODES;                     // N+1
    int*    aux  = rowp + N_NODES + 1;                // NTILES
    int*    adj  = aux + NTILES;                      // ET

    const int B = 256;
    const int EB = (ET + B - 1) / B;

    hipMemsetAsync(cnt, 0, N_NODES * sizeof(int), stream);
    count_kernel<<<EB, B, 0, stream>>>(ei, cnt);
    scanA_kernel<<<NTILES, SCAN_TILE, 0, stream>>>(cnt, rowp, aux);
    scanB_kernel<<<1, SCAN_TILE, 0, stream>>>(aux, rowp);
    scanC_kernel<<<NTILES, SCAN_TILE, 0, stream>>>(aux, rowp, cnt);
    fill_kernel<<<EB, B, 0, stream>>>(ei, cnt, adj);

    lin1_kernel<<<(N_NODES / 8 + 3) / 4, 256, 0, stream>>>(x, W1, as1, ad1, h1, s1, t1);

    l1_kernel<<<N_NODES / 4, 256, 0, stream>>>(rowp, adj, h1, s1, t1,
                                               b1, W2, as2, ad2, h2, s2, t2);

    l2_kernel<<<N_NODES / 4, 256, 0, stream>>>(rowp, adj, h2, s2, t2, b2, out);
}

// Round 10
// 298.820 us; speedup vs baseline: 2.5316x; 1.0799x over previous
//
#include <hip/hip_runtime.h>
#include <hip/hip_fp16.h>
#include <math.h>

#define N_NODES 50000
#define N_EDGES 800000
#define ET (N_EDGES + N_NODES)   // edges + self loops
#define IN_DIM 128
#define H1DIM 64                 // HEADS*HID
#define HEADS 8
#define HID 8
#define OUT_DIM 64
#define NEG_SLOPE 0.2f

#define SCAN_TILE 256
#define NTILES ((N_NODES + SCAN_TILE - 1) / SCAN_TILE)   // 196
#define RC 8                      // cached score iterations per lane (deg <= 57+slot)
#define PF 4                      // prefetched feature-row iterations (deg <= 32)

#define LIN1_WAVES (N_NODES / 8)                 // 6250
#define LIN1_BLOCKS ((LIN1_WAVES + 3) / 4)       // 1563
#define EB ((ET + 255) / 256)                    // 3321

__device__ __forceinline__ float lrelu(float v) { return v >= 0.f ? v : NEG_SLOPE * v; }

__device__ __forceinline__ float rdlane(float v, int l) {
    return __int_as_float(__builtin_amdgcn_readlane(__float_as_int(v), l));
}

// unpack 8 fp16 (raw uint4) and FMA into a[8]
__device__ __forceinline__ void fma8raw(uint4 u, float alpha, float* a) {
    float2 f0 = __half22float2(*(const __half2*)&u.x);
    float2 f1 = __half22float2(*(const __half2*)&u.y);
    float2 f2 = __half22float2(*(const __half2*)&u.z);
    float2 f3 = __half22float2(*(const __half2*)&u.w);
    a[0] += f0.x * alpha; a[1] += f0.y * alpha;
    a[2] += f1.x * alpha; a[3] += f1.y * alpha;
    a[4] += f2.x * alpha; a[5] += f2.y * alpha;
    a[6] += f3.x * alpha; a[7] += f3.y * alpha;
}

__device__ __forceinline__ void fma8h(const __half* __restrict__ base, float alpha, float* a) {
    fma8raw(*reinterpret_cast<const uint4*>(base), alpha, a);
}

// edge_index is int32 on device (validated round 4)
__device__ __forceinline__ void edge_nodes(const int* __restrict__ ei, int e, int& s, int& d) {
    if (e < N_EDGES) { s = ei[e]; d = ei[N_EDGES + e]; }
    else             { s = e - N_EDGES; d = s; }
}

// ---------------- fused: lin1 (blocks [0,LIN1_BLOCKS)) + edge count (rest) ----------------

__global__ __launch_bounds__(256) void cl1_kernel(
    const int* __restrict__ ei, int* __restrict__ cnt,
    const float* __restrict__ x, const float* __restrict__ W1,
    const float* __restrict__ a_src, const float* __restrict__ a_dst,
    __half* __restrict__ h1, float* __restrict__ ssrc, float* __restrict__ sdst)
{
    if (blockIdx.x >= LIN1_BLOCKS) {
        // ---- count part ----
        int i = (blockIdx.x - LIN1_BLOCKS) * 256 + threadIdx.x;
        if (i >= ET) return;
        int s, d; edge_nodes(ei, i, s, d);
        atomicAdd(&cnt[d], 1);
        return;
    }
    // ---- lin1 part: 8 nodes per wave ----
    int wid = threadIdx.x >> 6, t = threadIdx.x & 63;
    int g = blockIdx.x * 4 + wid;
    if (g >= LIN1_WAVES) return;
    int n0 = g * 8;

    float x0[8], x1[8];
    #pragma unroll
    for (int nn = 0; nn < 8; ++nn) {
        x0[nn] = x[(n0 + nn) * IN_DIM + t];
        x1[nn] = x[(n0 + nn) * IN_DIM + 64 + t];
    }
    float acc[8] = {0,0,0,0,0,0,0,0};
    #pragma unroll 8
    for (int k = 0; k < 64; ++k) {
        float w = W1[k * 64 + t];
        #pragma unroll
        for (int nn = 0; nn < 8; ++nn) acc[nn] += rdlane(x0[nn], k) * w;
    }
    #pragma unroll 8
    for (int k = 0; k < 64; ++k) {
        float w = W1[(k + 64) * 64 + t];
        #pragma unroll
        for (int nn = 0; nn < 8; ++nn) acc[nn] += rdlane(x1[nn], k) * w;
    }

    float av = a_src[t], bv = a_dst[t];
    #pragma unroll
    for (int nn = 0; nn < 8; ++nn) {
        int n = n0 + nn;
        h1[n * 64 + t] = __float2half(acc[nn]);
        float rs = acc[nn] * av, rd = acc[nn] * bv;
        rs += __shfl_xor(rs, 1); rs += __shfl_xor(rs, 2); rs += __shfl_xor(rs, 4);
        rd += __shfl_xor(rd, 1); rd += __shfl_xor(rd, 2); rd += __shfl_xor(rd, 4);
        if ((t & 7) == 0) { ssrc[n * 8 + (t >> 3)] = rs; sdst[n * 8 + (t >> 3)] = rd; }
    }
}

// ---------------- scans ----------------

__global__ __launch_bounds__(SCAN_TILE) void scanA_kernel(
    const int* __restrict__ cnt, int* __restrict__ row, int* __restrict__ aux)
{
    __shared__ int sh[SCAN_TILE];
    int t = threadIdx.x, i = blockIdx.x * SCAN_TILE + t;
    int v = (i < N_NODES) ? cnt[i] : 0;
    sh[t] = v;
    __syncthreads();
    #pragma unroll
    for (int off = 1; off < SCAN_TILE; off <<= 1) {
        int add = (t >= off) ? sh[t - off] : 0;
        __syncthreads();
        sh[t] += add;
        __syncthreads();
    }
    if (i < N_NODES) row[i] = sh[t] - v;
    if (t == SCAN_TILE - 1) aux[blockIdx.x] = sh[t];
}

__global__ __launch_bounds__(SCAN_TILE) void scanB_kernel(int* __restrict__ aux, int* __restrict__ row) {
    __shared__ int sh[SCAN_TILE];
    int t = threadIdx.x;
    int v = (t < NTILES) ? aux[t] : 0;
    sh[t] = v;
    __syncthreads();
    #pragma unroll
    for (int off = 1; off < SCAN_TILE; off <<= 1) {
        int add = (t >= off) ? sh[t - off] : 0;
        __syncthreads();
        sh[t] += add;
        __syncthreads();
    }
    if (t < NTILES) aux[t] = sh[t] - v;
    if (t == NTILES - 1) row[N_NODES] = sh[t];
}

__global__ __launch_bounds__(SCAN_TILE) void scanC_kernel(
    const int* __restrict__ aux, int* __restrict__ row, int* __restrict__ cursor)
{
    int i = blockIdx.x * SCAN_TILE + threadIdx.x;
    if (i >= N_NODES) return;
    int r = row[i] + aux[i >> 8];
    row[i] = r;
    cursor[i] = r;
}

__global__ void fill_kernel(const int* __restrict__ ei, int* __restrict__ cursor, int* __restrict__ adj) {
    int i = blockIdx.x * blockDim.x + threadIdx.x;
    if (i >= ET) return;
    int s, d; edge_nodes(ei, i, s, d);
    int pos = atomicAdd(&cursor[d], 1);
    adj[pos] = s;
}

// ---------------- layer-1 node kernel (register prefetch) ----------------

__global__ __launch_bounds__(256) void l1_kernel(
    const int* __restrict__ row, const int* __restrict__ adj,
    const __half* __restrict__ h1, const float* __restrict__ s1, const float* __restrict__ t1,
    const float* __restrict__ b1, const float* __restrict__ W2,
    const float* __restrict__ as2, const float* __restrict__ ad2,
    __half* __restrict__ h2, float* __restrict__ s2, float* __restrict__ t2)
{
    int wid = threadIdx.x >> 6, t = threadIdx.x & 63;
    int n = blockIdx.x * 4 + wid;
    int beg = row[n], end = row[n + 1];
    int slot = t >> 3, h = t & 7;
    float sd = t1[n * 8 + h];
    const int e0 = beg + slot;

    // pass 1: gather scores AND prefetch first PF feature rows (independent rounds)
    int   sv[RC];
    float p[RC];
    uint4 raw[PF];
    float m = -3e38f;
    #pragma unroll
    for (int it = 0; it < RC; ++it) {
        int e = e0 + it * 8;
        bool ok = e < end;
        int s = ok ? adj[e] : n;
        sv[it] = s;
        float v = ok ? lrelu(s1[s * 8 + h] + sd) : -3e38f;
        p[it] = v;
        m = fmaxf(m, v);
        if (it < PF) raw[it] = *reinterpret_cast<const uint4*>(h1 + (size_t)s * 64 + h * 8);
    }
    for (int e = e0 + RC * 8; e < end; e += 8)      // improbable tail
        m = fmaxf(m, lrelu(s1[adj[e] * 8 + h] + sd));
    m = fmaxf(m, __shfl_xor(m, 8));
    m = fmaxf(m, __shfl_xor(m, 16));
    m = fmaxf(m, __shfl_xor(m, 32));

    float den = 0.f;
    #pragma unroll
    for (int it = 0; it < RC; ++it) {
        float pe = __expf(p[it] - m);               // empty slots -> 0
        p[it] = pe;
        den += pe;
    }
    for (int e = e0 + RC * 8; e < end; e += 8)
        den += __expf(lrelu(s1[adj[e] * 8 + h] + sd) - m);
    den += __shfl_xor(den, 8);
    den += __shfl_xor(den, 16);
    den += __shfl_xor(den, 32);
    float inv = 1.f / (den + 1e-16f);

    // aggregate: prefetched rows unconditionally (alpha=0 for empty slots)
    float a[8] = {0,0,0,0,0,0,0,0};
    #pragma unroll
    for (int it = 0; it < PF; ++it) fma8raw(raw[it], p[it] * inv, a);
    #pragma unroll
    for (int it = PF; it < RC; ++it) {
        int e = e0 + it * 8;
        if (e < end) fma8h(h1 + (size_t)sv[it] * 64 + h * 8, p[it] * inv, a);
    }
    for (int e = e0 + RC * 8; e < end; e += 8) {
        int s = adj[e];
        float alpha = __expf(lrelu(s1[s * 8 + h] + sd) - m) * inv;
        fma8h(h1 + (size_t)s * 64 + h * 8, alpha, a);
    }
    #pragma unroll
    for (int mk = 8; mk <= 32; mk <<= 1) {
        #pragma unroll
        for (int j = 0; j < 8; ++j) a[j] += __shfl_xor(a[j], mk);
    }

    // redistribute: lane t needs channel t = head (t>>3), offset (t&7)
    float ha = 0.f;
    #pragma unroll
    for (int j = 0; j < 8; ++j) {
        float v = __shfl(a[j], t >> 3);
        if ((t & 7) == j) ha = v;
    }

    // bias + ELU
    ha += b1[t];
    ha = ha > 0.f ? ha : (__expf(ha) - 1.f);

    // fused lin2
    float acc2 = 0.f;
    #pragma unroll 8
    for (int k = 0; k < 64; ++k) acc2 += __shfl(ha, k) * W2[k * 64 + t];
    h2[n * 64 + t] = __float2half(acc2);

    // layer-2 scores
    float rs = acc2 * as2[t], rd = acc2 * ad2[t];
    #pragma unroll
    for (int mk = 32; mk >= 1; mk >>= 1) {
        rs += __shfl_xor(rs, mk);
        rd += __shfl_xor(rd, mk);
    }
    if (t == 0) { s2[n] = rs; t2[n] = rd; }
}

// ---------------- layer-2 node kernel (register prefetch) ----------------

__global__ __launch_bounds__(256) void l2_kernel(
    const int* __restrict__ row, const int* __restrict__ adj,
    const __half* __restrict__ h2, const float* __restrict__ s2, const float* __restrict__ t2,
    const float* __restrict__ b2, float* __restrict__ out)
{
    int wid = threadIdx.x >> 6, t = threadIdx.x & 63;
    int n = blockIdx.x * 4 + wid;
    int beg = row[n], end = row[n + 1];
    int slot = t >> 3, g = t & 7;
    float sd = t2[n];
    const int e0 = beg + slot;

    int   sv[RC];
    float p[RC];
    uint4 raw[PF];
    float m = -3e38f;
    #pragma unroll
    for (int it = 0; it < RC; ++it) {
        int e = e0 + it * 8;
        bool ok = e < end;
        int s = ok ? adj[e] : n;
        sv[it] = s;
        float v = ok ? lrelu(s2[s] + sd) : -3e38f;
        p[it] = v;
        m = fmaxf(m, v);
        if (it < PF) raw[it] = *reinterpret_cast<const uint4*>(h2 + (size_t)s * 64 + g * 8);
    }
    for (int e = e0 + RC * 8; e < end; e += 8)
        m = fmaxf(m, lrelu(s2[adj[e]] + sd));
    m = fmaxf(m, __shfl_xor(m, 8));
    m = fmaxf(m, __shfl_xor(m, 16));
    m = fmaxf(m, __shfl_xor(m, 32));

    float den = 0.f;
    #pragma unroll
    for (int it = 0; it < RC; ++it) {
        float pe = __expf(p[it] - m);
        p[it] = pe;
        den += pe;
    }
    for (int e = e0 + RC * 8; e < end; e += 8)
        den += __expf(lrelu(s2[adj[e]] + sd) - m);
    den += __shfl_xor(den, 8);
    den += __shfl_xor(den, 16);
    den += __shfl_xor(den, 32);
    float inv = 1.f / (den + 1e-16f);

    float a[8] = {0,0,0,0,0,0,0,0};
    #pragma unroll
    for (int it = 0; it < PF; ++it) fma8raw(raw[it], p[it] * inv, a);
    #pragma unroll
    for (int it = PF; it < RC; ++it) {
        int e = e0 + it * 8;
        if (e < end) fma8h(h2 + (size_t)sv[it] * 64 + g * 8, p[it] * inv, a);
    }
    for (int e = e0 + RC * 8; e < end; e += 8) {
        int s = adj[e];
        float alpha = __expf(lrelu(s2[s] + sd) - m) * inv;
        fma8h(h2 + (size_t)s * 64 + g * 8, alpha, a);
    }
    #pragma unroll
    for (int mk = 8; mk <= 32; mk <<= 1) {
        #pragma unroll
        for (int j = 0; j < 8; ++j) a[j] += __shfl_xor(a[j], mk);
    }
    if (slot == 0) {
        float4 o0 = make_float4(a[0] + b2[g * 8 + 0], a[1] + b2[g * 8 + 1],
                                a[2] + b2[g * 8 + 2], a[3] + b2[g * 8 + 3]);
        float4 o1 = make_float4(a[4] + b2[g * 8 + 4], a[5] + b2[g * 8 + 5],
                                a[6] + b2[g * 8 + 6], a[7] + b2[g * 8 + 7]);
        float4* op = (float4*)(out + (size_t)n * 64 + g * 8);
        op[0] = o0; op[1] = o1;
    }
}

extern "C" void kernel_launch(void* const* d_in, const int* in_sizes, int n_in,
                              void* d_out, int out_size, void* d_ws, size_t ws_size,
                              hipStream_t stream)
{
    const float* x   = (const float*)d_in[0];
    const int* ei    = (const int*)d_in[1];
    const float* W1  = (const float*)d_in[2];
    const float* as1 = (const float*)d_in[3];
    const float* ad1 = (const float*)d_in[4];
    const float* b1  = (const float*)d_in[5];
    const float* W2  = (const float*)d_in[6];
    const float* as2 = (const float*)d_in[7];
    const float* ad2 = (const float*)d_in[8];
    const float* b2  = (const float*)d_in[9];
    float* out = (float*)d_out;

    char* wsb = (char*)d_ws;
    __half* h1  = (__half*)wsb;                       // N*64 fp16
    __half* h2  = h1 + (size_t)N_NODES * 64;          // N*64 fp16
    float*  s1  = (float*)(h2 + (size_t)N_NODES * 64);// N*8
    float*  t1  = s1 + N_NODES * 8;                   // N*8
    float*  s2  = t1 + N_NODES * 8;                   // N
    float*  t2  = s2 + N_NODES;                       // N
    int*    cnt = (int*)(t2 + N_NODES);               // N (becomes cursor)
    int*    rowp = cnt + N_NODES;                     // N+1
    int*    aux  = rowp + N_NODES + 1;                // NTILES
    int*    adj  = aux + NTILES;                      // ET

    hipMemsetAsync(cnt, 0, N_NODES * sizeof(int), stream);

    // fused lin1 + count (independent work, overlapped)
    cl1_kernel<<<LIN1_BLOCKS + EB, 256, 0, stream>>>(ei, cnt, x, W1, as1, ad1, h1, s1, t1);

    scanA_kernel<<<NTILES, SCAN_TILE, 0, stream>>>(cnt, rowp, aux);
    scanB_kernel<<<1, SCAN_TILE, 0, stream>>>(aux, rowp);
    scanC_kernel<<<NTILES, SCAN_TILE, 0, stream>>>(aux, rowp, cnt);
    fill_kernel<<<EB, 256, 0, stream>>>(ei, cnt, adj);

    l1_kernel<<<N_NODES / 4, 256, 0, stream>>>(rowp, adj, h1, s1, t1,
                                               b1, W2, as2, ad2, h2, s2, t2);

    l2_kernel<<<N_NODES / 4, 256, 0, stream>>>(rowp, adj, h2, s2, t2, b2, out);
}

// Round 11
// 272.051 us; speedup vs baseline: 2.7807x; 1.0984x over previous
//
#include <hip/hip_runtime.h>
#include <hip/hip_fp16.h>
#include <math.h>

#define N_NODES 50000
#define N_EDGES 800000
#define ET (N_EDGES + N_NODES)   // edges + self loops
#define IN_DIM 128
#define H1DIM 64                 // HEADS*HID
#define HEADS 8
#define HID 8
#define OUT_DIM 64
#define NEG_SLOPE 0.2f

#define SCAN_TILE 256
#define NTILES ((N_NODES + SCAN_TILE - 1) / SCAN_TILE)   // 196
#define RC 8                      // cached score iterations per lane (4 slots -> deg <= 32)
#define PF 6                      // prefetched feature-row iterations (deg <= 24)

#define LIN1_WAVES (N_NODES / 8)                 // 6250
#define LIN1_BLOCKS ((LIN1_WAVES + 3) / 4)       // 1563
#define EB ((ET + 255) / 256)                    // 3321

__device__ __forceinline__ float lrelu(float v) { return v >= 0.f ? v : NEG_SLOPE * v; }

__device__ __forceinline__ float rdlane(float v, int l) {
    return __int_as_float(__builtin_amdgcn_readlane(__float_as_int(v), l));
}

// unpack 8 fp16 (raw uint4) and FMA into a[8]
__device__ __forceinline__ void fma8raw(uint4 u, float alpha, float* a) {
    float2 f0 = __half22float2(*(const __half2*)&u.x);
    float2 f1 = __half22float2(*(const __half2*)&u.y);
    float2 f2 = __half22float2(*(const __half2*)&u.z);
    float2 f3 = __half22float2(*(const __half2*)&u.w);
    a[0] += f0.x * alpha; a[1] += f0.y * alpha;
    a[2] += f1.x * alpha; a[3] += f1.y * alpha;
    a[4] += f2.x * alpha; a[5] += f2.y * alpha;
    a[6] += f3.x * alpha; a[7] += f3.y * alpha;
}

__device__ __forceinline__ void fma8h(const __half* __restrict__ base, float alpha, float* a) {
    fma8raw(*reinterpret_cast<const uint4*>(base), alpha, a);
}

// edge_index is int32 on device (validated round 4)
__device__ __forceinline__ void edge_nodes(const int* __restrict__ ei, int e, int& s, int& d) {
    if (e < N_EDGES) { s = ei[e]; d = ei[N_EDGES + e]; }
    else             { s = e - N_EDGES; d = s; }
}

// ---------------- fused: lin1 (blocks [0,LIN1_BLOCKS)) + edge count (rest) ----------------

__global__ __launch_bounds__(256) void cl1_kernel(
    const int* __restrict__ ei, int* __restrict__ cnt,
    const float* __restrict__ x, const float* __restrict__ W1,
    const float* __restrict__ a_src, const float* __restrict__ a_dst,
    __half* __restrict__ h1, float* __restrict__ ssrc, float* __restrict__ sdst)
{
    if (blockIdx.x >= LIN1_BLOCKS) {
        int i = (blockIdx.x - LIN1_BLOCKS) * 256 + threadIdx.x;
        if (i >= ET) return;
        int s, d; edge_nodes(ei, i, s, d);
        atomicAdd(&cnt[d], 1);
        return;
    }
    int wid = threadIdx.x >> 6, t = threadIdx.x & 63;
    int g = blockIdx.x * 4 + wid;
    if (g >= LIN1_WAVES) return;
    int n0 = g * 8;

    float x0[8], x1[8];
    #pragma unroll
    for (int nn = 0; nn < 8; ++nn) {
        x0[nn] = x[(n0 + nn) * IN_DIM + t];
        x1[nn] = x[(n0 + nn) * IN_DIM + 64 + t];
    }
    float acc[8] = {0,0,0,0,0,0,0,0};
    #pragma unroll 8
    for (int k = 0; k < 64; ++k) {
        float w = W1[k * 64 + t];
        #pragma unroll
        for (int nn = 0; nn < 8; ++nn) acc[nn] += rdlane(x0[nn], k) * w;
    }
    #pragma unroll 8
    for (int k = 0; k < 64; ++k) {
        float w = W1[(k + 64) * 64 + t];
        #pragma unroll
        for (int nn = 0; nn < 8; ++nn) acc[nn] += rdlane(x1[nn], k) * w;
    }

    float av = a_src[t], bv = a_dst[t];
    #pragma unroll
    for (int nn = 0; nn < 8; ++nn) {
        int n = n0 + nn;
        h1[n * 64 + t] = __float2half(acc[nn]);
        float rs = acc[nn] * av, rd = acc[nn] * bv;
        rs += __shfl_xor(rs, 1); rs += __shfl_xor(rs, 2); rs += __shfl_xor(rs, 4);
        rd += __shfl_xor(rd, 1); rd += __shfl_xor(rd, 2); rd += __shfl_xor(rd, 4);
        if ((t & 7) == 0) { ssrc[n * 8 + (t >> 3)] = rs; sdst[n * 8 + (t >> 3)] = rd; }
    }
}

// ---------------- scans ----------------

__global__ __launch_bounds__(SCAN_TILE) void scanA_kernel(
    const int* __restrict__ cnt, int* __restrict__ row, int* __restrict__ aux)
{
    __shared__ int sh[SCAN_TILE];
    int t = threadIdx.x, i = blockIdx.x * SCAN_TILE + t;
    int v = (i < N_NODES) ? cnt[i] : 0;
    sh[t] = v;
    __syncthreads();
    #pragma unroll
    for (int off = 1; off < SCAN_TILE; off <<= 1) {
        int add = (t >= off) ? sh[t - off] : 0;
        __syncthreads();
        sh[t] += add;
        __syncthreads();
    }
    if (i < N_NODES) row[i] = sh[t] - v;
    if (t == SCAN_TILE - 1) aux[blockIdx.x] = sh[t];
}

__global__ __launch_bounds__(SCAN_TILE) void scanB_kernel(int* __restrict__ aux, int* __restrict__ row) {
    __shared__ int sh[SCAN_TILE];
    int t = threadIdx.x;
    int v = (t < NTILES) ? aux[t] : 0;
    sh[t] = v;
    __syncthreads();
    #pragma unroll
    for (int off = 1; off < SCAN_TILE; off <<= 1) {
        int add = (t >= off) ? sh[t - off] : 0;
        __syncthreads();
        sh[t] += add;
        __syncthreads();
    }
    if (t < NTILES) aux[t] = sh[t] - v;
    if (t == NTILES - 1) row[N_NODES] = sh[t];
}

__global__ __launch_bounds__(SCAN_TILE) void scanC_kernel(
    const int* __restrict__ aux, int* __restrict__ row, int* __restrict__ cursor)
{
    int i = blockIdx.x * SCAN_TILE + threadIdx.x;
    if (i >= N_NODES) return;
    int r = row[i] + aux[i >> 8];
    row[i] = r;
    cursor[i] = r;
}

__global__ void fill_kernel(const int* __restrict__ ei, int* __restrict__ cursor, int* __restrict__ adj) {
    int i = blockIdx.x * blockDim.x + threadIdx.x;
    if (i >= ET) return;
    int s, d; edge_nodes(ei, i, s, d);
    int pos = atomicAdd(&cursor[d], 1);
    adj[pos] = s;
}

// ---------------- layer-1 node kernel: 2 nodes per wave ----------------
// lane t: half = t>>5 (node select), tt = t&31, slot = tt>>3 (4 slots), h = tt&7

__global__ __launch_bounds__(256) void l1_kernel(
    const int* __restrict__ row, const int* __restrict__ adj,
    const __half* __restrict__ h1, const float* __restrict__ s1, const float* __restrict__ t1,
    const float* __restrict__ b1, const float* __restrict__ W2,
    const float* __restrict__ as2, const float* __restrict__ ad2,
    __half* __restrict__ h2, float* __restrict__ s2, float* __restrict__ t2)
{
    int wid = threadIdx.x >> 6, t = threadIdx.x & 63;
    int half = t >> 5, tt = t & 31;
    int n = blockIdx.x * 8 + wid * 2 + half;
    int beg = row[n], end = row[n + 1];
    int slot = tt >> 3, h = tt & 7;
    float sd = t1[n * 8 + h];
    const int e0 = beg + slot;
    const int hb = half << 5;                     // half base lane

    // pass 1: gather scores + prefetch first PF feature rows
    int   sv[RC];
    float p[RC];
    uint4 raw[PF];
    float m = -3e38f;
    #pragma unroll
    for (int it = 0; it < RC; ++it) {
        int e = e0 + it * 4;
        bool ok = e < end;
        int s = ok ? adj[e] : n;
        sv[it] = s;
        float v = ok ? lrelu(s1[s * 8 + h] + sd) : -3e38f;
        p[it] = v;
        m = fmaxf(m, v);
        if (it < PF) raw[it] = *reinterpret_cast<const uint4*>(h1 + (size_t)s * 64 + h * 8);
    }
    for (int e = e0 + RC * 4; e < end; e += 4)    // improbable tail (deg > 32)
        m = fmaxf(m, lrelu(s1[adj[e] * 8 + h] + sd));
    m = fmaxf(m, __shfl_xor(m, 8));
    m = fmaxf(m, __shfl_xor(m, 16));

    float den = 0.f;
    #pragma unroll
    for (int it = 0; it < RC; ++it) {
        float pe = __expf(p[it] - m);             // empty slots -> 0
        p[it] = pe;
        den += pe;
    }
    for (int e = e0 + RC * 4; e < end; e += 4)
        den += __expf(lrelu(s1[adj[e] * 8 + h] + sd) - m);
    den += __shfl_xor(den, 8);
    den += __shfl_xor(den, 16);
    float inv = 1.f / (den + 1e-16f);

    // aggregate: lane accumulates channels h*8..h*8+7 of its node
    float a[8] = {0,0,0,0,0,0,0,0};
    #pragma unroll
    for (int it = 0; it < PF; ++it) fma8raw(raw[it], p[it] * inv, a);
    #pragma unroll
    for (int it = PF; it < RC; ++it) {
        int e = e0 + it * 4;
        if (e < end) fma8h(h1 + (size_t)sv[it] * 64 + h * 8, p[it] * inv, a);
    }
    for (int e = e0 + RC * 4; e < end; e += 4) {
        int s = adj[e];
        float alpha = __expf(lrelu(s1[s * 8 + h] + sd) - m) * inv;
        fma8h(h1 + (size_t)s * 64 + h * 8, alpha, a);
    }
    #pragma unroll
    for (int j = 0; j < 8; ++j) {
        a[j] += __shfl_xor(a[j], 8);
        a[j] += __shfl_xor(a[j], 16);
    }
    // now lanes hb+0..hb+7 (slot==0) hold the node's 64 channels: lane hb+h has a[0..7] = ch h*8..h*8+7

    // redistribute: this lane needs ch0 = tt (j = tt&7, src hb + (tt>>3)) and ch1 = tt+32 (src hb + (tt>>3) + 4)
    float ha0 = 0.f, ha1 = 0.f;
    int srcA = hb + (tt >> 3);
    #pragma unroll
    for (int j = 0; j < 8; ++j) {
        float vA = __shfl(a[j], srcA);
        float vB = __shfl(a[j], srcA + 4);
        if ((tt & 7) == j) { ha0 = vA; ha1 = vB; }
    }

    // bias + ELU
    ha0 += b1[tt];
    ha1 += b1[tt + 32];
    ha0 = ha0 > 0.f ? ha0 : (__expf(ha0) - 1.f);
    ha1 = ha1 > 0.f ? ha1 : (__expf(ha1) - 1.f);

    // fused lin2: node's 64 channels live as ha0 (ch tt) / ha1 (ch tt+32) in this half
    float c0 = 0.f, c1 = 0.f;
    #pragma unroll 8
    for (int k = 0; k < 32; ++k) {
        float w = __shfl(ha0, hb + k);
        c0 += w * W2[k * 64 + tt];
        c1 += w * W2[k * 64 + tt + 32];
    }
    #pragma unroll 8
    for (int k = 0; k < 32; ++k) {
        float w = __shfl(ha1, hb + k);
        c0 += w * W2[(k + 32) * 64 + tt];
        c1 += w * W2[(k + 32) * 64 + tt + 32];
    }
    h2[n * 64 + tt]      = __float2half(c0);
    h2[n * 64 + tt + 32] = __float2half(c1);

    // layer-2 scores (reduce within 32-lane half)
    float rs = c0 * as2[tt] + c1 * as2[tt + 32];
    float rd = c0 * ad2[tt] + c1 * ad2[tt + 32];
    #pragma unroll
    for (int mk = 16; mk >= 1; mk >>= 1) {
        rs += __shfl_xor(rs, mk);
        rd += __shfl_xor(rd, mk);
    }
    if (tt == 0) { s2[n] = rs; t2[n] = rd; }
}

// ---------------- layer-2 node kernel: 2 nodes per wave ----------------
// lane t: half = t>>5, tt = t&31, slot = tt>>3 (4 slots), g = tt&7 (channel group)

__global__ __launch_bounds__(256) void l2_kernel(
    const int* __restrict__ row, const int* __restrict__ adj,
    const __half* __restrict__ h2, const float* __restrict__ s2, const float* __restrict__ t2,
    const float* __restrict__ b2, float* __restrict__ out)
{
    int wid = threadIdx.x >> 6, t = threadIdx.x & 63;
    int half = t >> 5, tt = t & 31;
    int n = blockIdx.x * 8 + wid * 2 + half;
    int beg = row[n], end = row[n + 1];
    int slot = tt >> 3, g = tt & 7;
    float sd = t2[n];
    const int e0 = beg + slot;

    int   sv[RC];
    float p[RC];
    uint4 raw[PF];
    float m = -3e38f;
    #pragma unroll
    for (int it = 0; it < RC; ++it) {
        int e = e0 + it * 4;
        bool ok = e < end;
        int s = ok ? adj[e] : n;
        sv[it] = s;
        float v = ok ? lrelu(s2[s] + sd) : -3e38f;
        p[it] = v;
        m = fmaxf(m, v);
        if (it < PF) raw[it] = *reinterpret_cast<const uint4*>(h2 + (size_t)s * 64 + g * 8);
    }
    for (int e = e0 + RC * 4; e < end; e += 4)
        m = fmaxf(m, lrelu(s2[adj[e]] + sd));
    m = fmaxf(m, __shfl_xor(m, 8));
    m = fmaxf(m, __shfl_xor(m, 16));

    float den = 0.f;
    #pragma unroll
    for (int it = 0; it < RC; ++it) {
        float pe = __expf(p[it] - m);
        p[it] = pe;
        den += pe;
    }
    for (int e = e0 + RC * 4; e < end; e += 4)
        den += __expf(lrelu(s2[adj[e]] + sd) - m);
    den += __shfl_xor(den, 8);
    den += __shfl_xor(den, 16);
    float inv = 1.f / (den + 1e-16f);

    float a[8] = {0,0,0,0,0,0,0,0};
    #pragma unroll
    for (int it = 0; it < PF; ++it) fma8raw(raw[it], p[it] * inv, a);
    #pragma unroll
    for (int it = PF; it < RC; ++it) {
        int e = e0 + it * 4;
        if (e < end) fma8h(h2 + (size_t)sv[it] * 64 + g * 8, p[it] * inv, a);
    }
    for (int e = e0 + RC * 4; e < end; e += 4) {
        int s = adj[e];
        float alpha = __expf(lrelu(s2[s] + sd) - m) * inv;
        fma8h(h2 + (size_t)s * 64 + g * 8, alpha, a);
    }
    #pragma unroll
    for (int j = 0; j < 8; ++j) {
        a[j] += __shfl_xor(a[j], 8);
        a[j] += __shfl_xor(a[j], 16);
    }
    if (slot == 0) {
        float4 o0 = make_float4(a[0] + b2[g * 8 + 0], a[1] + b2[g * 8 + 1],
                                a[2] + b2[g * 8 + 2], a[3] + b2[g * 8 + 3]);
        float4 o1 = make_float4(a[4] + b2[g * 8 + 4], a[5] + b2[g * 8 + 5],
                                a[6] + b2[g * 8 + 6], a[7] + b2[g * 8 + 7]);
        float4* op = (float4*)(out + (size_t)n * 64 + g * 8);
        op[0] = o0; op[1] = o1;
    }
}

extern "C" void kernel_launch(void* const* d_in, const int* in_sizes, int n_in,
                              void* d_out, int out_size, void* d_ws, size_t ws_size,
                              hipStream_t stream)
{
    const float* x   = (const float*)d_in[0];
    const int* ei    = (const int*)d_in[1];
    const float* W1  = (const float*)d_in[2];
    const float* as1 = (const float*)d_in[3];
    const float* ad1 = (const float*)d_in[4];
    const float* b1  = (const float*)d_in[5];
    const float* W2  = (const float*)d_in[6];
    const float* as2 = (const float*)d_in[7];
    const float* ad2 = (const float*)d_in[8];
    const float* b2  = (const float*)d_in[9];
    float* out = (float*)d_out;

    char* wsb = (char*)d_ws;
    __half* h1  = (__half*)wsb;                       // N*64 fp16
    __half* h2  = h1 + (size_t)N_NODES * 64;          // N*64 fp16
    float*  s1  = (float*)(h2 + (size_t)N_NODES * 64);// N*8
    float*  t1  = s1 + N_NODES * 8;                   // N*8
    float*  s2  = t1 + N_NODES * 8;                   // N
    float*  t2  = s2 + N_NODES;                       // N
    int*    cnt = (int*)(t2 + N_NODES);               // N (becomes cursor)
    int*    rowp = cnt + N_NODES;                     // N+1
    int*    aux  = rowp + N_NODES + 1;                // NTILES
    int*    adj  = aux + NTILES;                      // ET

    hipMemsetAsync(cnt, 0, N_NODES * sizeof(int), stream);

    cl1_kernel<<<LIN1_BLOCKS + EB, 256, 0, stream>>>(ei, cnt, x, W1, as1, ad1, h1, s1, t1);

    scanA_kernel<<<NTILES, SCAN_TILE, 0, stream>>>(cnt, rowp, aux);
    scanB_kernel<<<1, SCAN_TILE, 0, stream>>>(aux, rowp);
    scanC_kernel<<<NTILES, SCAN_TILE, 0, stream>>>(aux, rowp, cnt);
    fill_kernel<<<EB, 256, 0, stream>>>(ei, cnt, adj);

    l1_kernel<<<N_NODES / 8, 256, 0, stream>>>(rowp, adj, h1, s1, t1,
                                               b1, W2, as2, ad2, h2, s2, t2);

    l2_kernel<<<N_NODES / 8, 256, 0, stream>>>(rowp, adj, h2, s2, t2, b2, out);
}

// Round 12
// 231.015 us; speedup vs baseline: 3.2747x; 1.1776x over previous
//
#include <hip/hip_runtime.h>
#include <hip/hip_fp16.h>
#include <math.h>

#define N_NODES 50000
#define N_EDGES 800000
#define ET (N_EDGES + N_NODES)   // edges + self loops
#define IN_DIM 128
#define H1DIM 64                 // HEADS*HID
#define HEADS 8
#define HID 8
#define OUT_DIM 64
#define NEG_SLOPE 0.2f

#define SCAN_TILE 256
#define NTILES ((N_NODES + SCAN_TILE - 1) / SCAN_TILE)   // 196
#define RC 8                      // cached score iterations per lane (4 slots -> deg <= 32)
#define PF 6                      // prefetched feature-row iterations (deg <= 24)

#define LIN1_WAVES (N_NODES / 8)                 // 6250
#define LIN1_BLOCKS ((LIN1_WAVES + 3) / 4)       // 1563
#define EB ((ET + 255) / 256)                    // 3321

__device__ __forceinline__ float lrelu(float v) { return v >= 0.f ? v : NEG_SLOPE * v; }

__device__ __forceinline__ float rdlane(float v, int l) {
    return __int_as_float(__builtin_amdgcn_readlane(__float_as_int(v), l));
}

// unpack 8 fp16 (raw uint4) and FMA into a[8]
__device__ __forceinline__ void fma8raw(uint4 u, float alpha, float* a) {
    float2 f0 = __half22float2(*(const __half2*)&u.x);
    float2 f1 = __half22float2(*(const __half2*)&u.y);
    float2 f2 = __half22float2(*(const __half2*)&u.z);
    float2 f3 = __half22float2(*(const __half2*)&u.w);
    a[0] += f0.x * alpha; a[1] += f0.y * alpha;
    a[2] += f1.x * alpha; a[3] += f1.y * alpha;
    a[4] += f2.x * alpha; a[5] += f2.y * alpha;
    a[6] += f3.x * alpha; a[7] += f3.y * alpha;
}

__device__ __forceinline__ void fma8h(const __half* __restrict__ base, float alpha, float* a) {
    fma8raw(*reinterpret_cast<const uint4*>(base), alpha, a);
}

// edge_index is int32 on device (validated round 4)
__device__ __forceinline__ void edge_nodes(const int* __restrict__ ei, int e, int& s, int& d) {
    if (e < N_EDGES) { s = ei[e]; d = ei[N_EDGES + e]; }
    else             { s = e - N_EDGES; d = s; }
}

// ---------------- fused: lin1 (blocks [0,LIN1_BLOCKS)) + count-with-pos (rest) ----------------

__global__ __launch_bounds__(256) void cl1_kernel(
    const int* __restrict__ ei, int* __restrict__ cnt, int* __restrict__ pos,
    const float* __restrict__ x, const float* __restrict__ W1,
    const float* __restrict__ a_src, const float* __restrict__ a_dst,
    __half* __restrict__ h1, float* __restrict__ ssrc, float* __restrict__ sdst)
{
    if (blockIdx.x >= LIN1_BLOCKS) {
        int i = (blockIdx.x - LIN1_BLOCKS) * 256 + threadIdx.x;
        if (i >= ET) return;
        int s, d; edge_nodes(ei, i, s, d);
        pos[i] = atomicAdd(&cnt[d], 1);      // pay the atomic once, keep the return
        return;
    }
    int wid = threadIdx.x >> 6, t = threadIdx.x & 63;
    int g = blockIdx.x * 4 + wid;
    if (g >= LIN1_WAVES) return;
    int n0 = g * 8;

    float x0[8], x1[8];
    #pragma unroll
    for (int nn = 0; nn < 8; ++nn) {
        x0[nn] = x[(n0 + nn) * IN_DIM + t];
        x1[nn] = x[(n0 + nn) * IN_DIM + 64 + t];
    }
    float acc[8] = {0,0,0,0,0,0,0,0};
    #pragma unroll 8
    for (int k = 0; k < 64; ++k) {
        float w = W1[k * 64 + t];
        #pragma unroll
        for (int nn = 0; nn < 8; ++nn) acc[nn] += rdlane(x0[nn], k) * w;
    }
    #pragma unroll 8
    for (int k = 0; k < 64; ++k) {
        float w = W1[(k + 64) * 64 + t];
        #pragma unroll
        for (int nn = 0; nn < 8; ++nn) acc[nn] += rdlane(x1[nn], k) * w;
    }

    float av = a_src[t], bv = a_dst[t];
    #pragma unroll
    for (int nn = 0; nn < 8; ++nn) {
        int n = n0 + nn;
        h1[n * 64 + t] = __float2half(acc[nn]);
        float rs = acc[nn] * av, rd = acc[nn] * bv;
        rs += __shfl_xor(rs, 1); rs += __shfl_xor(rs, 2); rs += __shfl_xor(rs, 4);
        rd += __shfl_xor(rd, 1); rd += __shfl_xor(rd, 2); rd += __shfl_xor(rd, 4);
        if ((t & 7) == 0) { ssrc[n * 8 + (t >> 3)] = rs; sdst[n * 8 + (t >> 3)] = rd; }
    }
}

// ---------------- scans ----------------

__global__ __launch_bounds__(SCAN_TILE) void scanA_kernel(
    const int* __restrict__ cnt, int* __restrict__ row, int* __restrict__ aux)
{
    __shared__ int sh[SCAN_TILE];
    int t = threadIdx.x, i = blockIdx.x * SCAN_TILE + t;
    int v = (i < N_NODES) ? cnt[i] : 0;
    sh[t] = v;
    __syncthreads();
    #pragma unroll
    for (int off = 1; off < SCAN_TILE; off <<= 1) {
        int add = (t >= off) ? sh[t - off] : 0;
        __syncthreads();
        sh[t] += add;
        __syncthreads();
    }
    if (i < N_NODES) row[i] = sh[t] - v;
    if (t == SCAN_TILE - 1) aux[blockIdx.x] = sh[t];
}

__global__ __launch_bounds__(SCAN_TILE) void scanB_kernel(int* __restrict__ aux, int* __restrict__ row) {
    __shared__ int sh[SCAN_TILE];
    int t = threadIdx.x;
    int v = (t < NTILES) ? aux[t] : 0;
    sh[t] = v;
    __syncthreads();
    #pragma unroll
    for (int off = 1; off < SCAN_TILE; off <<= 1) {
        int add = (t >= off) ? sh[t - off] : 0;
        __syncthreads();
        sh[t] += add;
        __syncthreads();
    }
    if (t < NTILES) aux[t] = sh[t] - v;
    if (t == NTILES - 1) row[N_NODES] = sh[t];
}

__global__ __launch_bounds__(SCAN_TILE) void scanC_kernel(
    const int* __restrict__ aux, int* __restrict__ row)
{
    int i = blockIdx.x * SCAN_TILE + threadIdx.x;
    if (i >= N_NODES) return;
    row[i] += aux[i >> 8];
}

// atomic-free fill: position precomputed in cl1
__global__ void fill_kernel(const int* __restrict__ ei, const int* __restrict__ row,
                            const int* __restrict__ pos, int* __restrict__ adj)
{
    int i = blockIdx.x * blockDim.x + threadIdx.x;
    if (i >= ET) return;
    int s, d; edge_nodes(ei, i, s, d);
    adj[row[d] + pos[i]] = s;
}

// ---------------- layer-1 node kernel: 2 nodes per wave ----------------
// lane t: half = t>>5 (node select), tt = t&31, slot = tt>>3 (4 slots), h = tt&7

__global__ __launch_bounds__(256) void l1_kernel(
    const int* __restrict__ row, const int* __restrict__ adj,
    const __half* __restrict__ h1, const float* __restrict__ s1, const float* __restrict__ t1,
    const float* __restrict__ b1, const float* __restrict__ W2,
    const float* __restrict__ as2, const float* __restrict__ ad2,
    __half* __restrict__ h2, float* __restrict__ s2, float* __restrict__ t2)
{
    int wid = threadIdx.x >> 6, t = threadIdx.x & 63;
    int half = t >> 5, tt = t & 31;
    int n = blockIdx.x * 8 + wid * 2 + half;
    int beg = row[n], end = row[n + 1];
    int slot = tt >> 3, h = tt & 7;
    float sd = t1[n * 8 + h];
    const int e0 = beg + slot;
    const int hb = half << 5;                     // half base lane

    // pass 1: gather scores + prefetch first PF feature rows
    int   sv[RC];
    float p[RC];
    uint4 raw[PF];
    float m = -3e38f;
    #pragma unroll
    for (int it = 0; it < RC; ++it) {
        int e = e0 + it * 4;
        bool ok = e < end;
        int s = ok ? adj[e] : n;
        sv[it] = s;
        float v = ok ? lrelu(s1[s * 8 + h] + sd) : -3e38f;
        p[it] = v;
        m = fmaxf(m, v);
        if (it < PF) raw[it] = *reinterpret_cast<const uint4*>(h1 + (size_t)s * 64 + h * 8);
    }
    for (int e = e0 + RC * 4; e < end; e += 4)    // improbable tail (deg > 32)
        m = fmaxf(m, lrelu(s1[adj[e] * 8 + h] + sd));
    m = fmaxf(m, __shfl_xor(m, 8));
    m = fmaxf(m, __shfl_xor(m, 16));

    float den = 0.f;
    #pragma unroll
    for (int it = 0; it < RC; ++it) {
        float pe = __expf(p[it] - m);             // empty slots -> 0
        p[it] = pe;
        den += pe;
    }
    for (int e = e0 + RC * 4; e < end; e += 4)
        den += __expf(lrelu(s1[adj[e] * 8 + h] + sd) - m);
    den += __shfl_xor(den, 8);
    den += __shfl_xor(den, 16);
    float inv = 1.f / (den + 1e-16f);

    // aggregate: lane accumulates channels h*8..h*8+7 of its node
    float a[8] = {0,0,0,0,0,0,0,0};
    #pragma unroll
    for (int it = 0; it < PF; ++it) fma8raw(raw[it], p[it] * inv, a);
    #pragma unroll
    for (int it = PF; it < RC; ++it) {
        int e = e0 + it * 4;
        if (e < end) fma8h(h1 + (size_t)sv[it] * 64 + h * 8, p[it] * inv, a);
    }
    for (int e = e0 + RC * 4; e < end; e += 4) {
        int s = adj[e];
        float alpha = __expf(lrelu(s1[s * 8 + h] + sd) - m) * inv;
        fma8h(h1 + (size_t)s * 64 + h * 8, alpha, a);
    }
    #pragma unroll
    for (int j = 0; j < 8; ++j) {
        a[j] += __shfl_xor(a[j], 8);
        a[j] += __shfl_xor(a[j], 16);
    }

    // redistribute: this lane needs ch0 = tt and ch1 = tt+32
    float ha0 = 0.f, ha1 = 0.f;
    int srcA = hb + (tt >> 3);
    #pragma unroll
    for (int j = 0; j < 8; ++j) {
        float vA = __shfl(a[j], srcA);
        float vB = __shfl(a[j], srcA + 4);
        if ((tt & 7) == j) { ha0 = vA; ha1 = vB; }
    }

    // bias + ELU
    ha0 += b1[tt];
    ha1 += b1[tt + 32];
    ha0 = ha0 > 0.f ? ha0 : (__expf(ha0) - 1.f);
    ha1 = ha1 > 0.f ? ha1 : (__expf(ha1) - 1.f);

    // fused lin2
    float c0 = 0.f, c1 = 0.f;
    #pragma unroll 8
    for (int k = 0; k < 32; ++k) {
        float w = __shfl(ha0, hb + k);
        c0 += w * W2[k * 64 + tt];
        c1 += w * W2[k * 64 + tt + 32];
    }
    #pragma unroll 8
    for (int k = 0; k < 32; ++k) {
        float w = __shfl(ha1, hb + k);
        c0 += w * W2[(k + 32) * 64 + tt];
        c1 += w * W2[(k + 32) * 64 + tt + 32];
    }
    h2[n * 64 + tt]      = __float2half(c0);
    h2[n * 64 + tt + 32] = __float2half(c1);

    // layer-2 scores (reduce within 32-lane half)
    float rs = c0 * as2[tt] + c1 * as2[tt + 32];
    float rd = c0 * ad2[tt] + c1 * ad2[tt + 32];
    #pragma unroll
    for (int mk = 16; mk >= 1; mk >>= 1) {
        rs += __shfl_xor(rs, mk);
        rd += __shfl_xor(rd, mk);
    }
    if (tt == 0) { s2[n] = rs; t2[n] = rd; }
}

// ---------------- layer-2 node kernel: 2 nodes per wave ----------------

__global__ __launch_bounds__(256) void l2_kernel(
    const int* __restrict__ row, const int* __restrict__ adj,
    const __half* __restrict__ h2, const float* __restrict__ s2, const float* __restrict__ t2,
    const float* __restrict__ b2, float* __restrict__ out)
{
    int wid = threadIdx.x >> 6, t = threadIdx.x & 63;
    int half = t >> 5, tt = t & 31;
    int n = blockIdx.x * 8 + wid * 2 + half;
    int beg = row[n], end = row[n + 1];
    int slot = tt >> 3, g = tt & 7;
    float sd = t2[n];
    const int e0 = beg + slot;

    int   sv[RC];
    float p[RC];
    uint4 raw[PF];
    float m = -3e38f;
    #pragma unroll
    for (int it = 0; it < RC; ++it) {
        int e = e0 + it * 4;
        bool ok = e < end;
        int s = ok ? adj[e] : n;
        sv[it] = s;
        float v = ok ? lrelu(s2[s] + sd) : -3e38f;
        p[it] = v;
        m = fmaxf(m, v);
        if (it < PF) raw[it] = *reinterpret_cast<const uint4*>(h2 + (size_t)s * 64 + g * 8);
    }
    for (int e = e0 + RC * 4; e < end; e += 4)
        m = fmaxf(m, lrelu(s2[adj[e]] + sd));
    m = fmaxf(m, __shfl_xor(m, 8));
    m = fmaxf(m, __shfl_xor(m, 16));

    float den = 0.f;
    #pragma unroll
    for (int it = 0; it < RC; ++it) {
        float pe = __expf(p[it] - m);
        p[it] = pe;
        den += pe;
    }
    for (int e = e0 + RC * 4; e < end; e += 4)
        den += __expf(lrelu(s2[adj[e]] + sd) - m);
    den += __shfl_xor(den, 8);
    den += __shfl_xor(den, 16);
    float inv = 1.f / (den + 1e-16f);

    float a[8] = {0,0,0,0,0,0,0,0};
    #pragma unroll
    for (int it = 0; it < PF; ++it) fma8raw(raw[it], p[it] * inv, a);
    #pragma unroll
    for (int it = PF; it < RC; ++it) {
        int e = e0 + it * 4;
        if (e < end) fma8h(h2 + (size_t)sv[it] * 64 + g * 8, p[it] * inv, a);
    }
    for (int e = e0 + RC * 4; e < end; e += 4) {
        int s = adj[e];
        float alpha = __expf(lrelu(s2[s] + sd) - m) * inv;
        fma8h(h2 + (size_t)s * 64 + g * 8, alpha, a);
    }
    #pragma unroll
    for (int j = 0; j < 8; ++j) {
        a[j] += __shfl_xor(a[j], 8);
        a[j] += __shfl_xor(a[j], 16);
    }
    if (slot == 0) {
        float4 o0 = make_float4(a[0] + b2[g * 8 + 0], a[1] + b2[g * 8 + 1],
                                a[2] + b2[g * 8 + 2], a[3] + b2[g * 8 + 3]);
        float4 o1 = make_float4(a[4] + b2[g * 8 + 4], a[5] + b2[g * 8 + 5],
                                a[6] + b2[g * 8 + 6], a[7] + b2[g * 8 + 7]);
        float4* op = (float4*)(out + (size_t)n * 64 + g * 8);
        op[0] = o0; op[1] = o1;
    }
}

extern "C" void kernel_launch(void* const* d_in, const int* in_sizes, int n_in,
                              void* d_out, int out_size, void* d_ws, size_t ws_size,
                              hipStream_t stream)
{
    const float* x   = (const float*)d_in[0];
    const int* ei    = (const int*)d_in[1];
    const float* W1  = (const float*)d_in[2];
    const float* as1 = (const float*)d_in[3];
    const float* ad1 = (const float*)d_in[4];
    const float* b1  = (const float*)d_in[5];
    const float* W2  = (const float*)d_in[6];
    const float* as2 = (const float*)d_in[7];
    const float* ad2 = (const float*)d_in[8];
    const float* b2  = (const float*)d_in[9];
    float* out = (float*)d_out;

    char* wsb = (char*)d_ws;
    __half* h1  = (__half*)wsb;                       // N*64 fp16
    __half* h2  = h1 + (size_t)N_NODES * 64;          // N*64 fp16
    float*  s1  = (float*)(h2 + (size_t)N_NODES * 64);// N*8
    float*  t1  = s1 + N_NODES * 8;                   // N*8
    float*  s2  = t1 + N_NODES * 8;                   // N
    float*  t2  = s2 + N_NODES;                       // N
    int*    cnt = (int*)(t2 + N_NODES);               // N
    int*    rowp = cnt + N_NODES;                     // N+1
    int*    aux  = rowp + N_NODES + 1;                // NTILES
    int*    adj  = aux + NTILES;                      // ET
    int*    pos  = adj + ET;                          // ET

    hipMemsetAsync(cnt, 0, N_NODES * sizeof(int), stream);

    cl1_kernel<<<LIN1_BLOCKS + EB, 256, 0, stream>>>(ei, cnt, pos, x, W1, as1, ad1, h1, s1, t1);

    scanA_kernel<<<NTILES, SCAN_TILE, 0, stream>>>(cnt, rowp, aux);
    scanB_kernel<<<1, SCAN_TILE, 0, stream>>>(aux, rowp);
    scanC_kernel<<<NTILES, SCAN_TILE, 0, stream>>>(aux, rowp);
    fill_kernel<<<EB, 256, 0, stream>>>(ei, rowp, pos, adj);

    l1_kernel<<<N_NODES / 8, 256, 0, stream>>>(rowp, adj, h1, s1, t1,
                                               b1, W2, as2, ad2, h2, s2, t2);

    l2_kernel<<<N_NODES / 8, 256, 0, stream>>>(rowp, adj, h2, s2, t2, b2, out);
}